// Round 7
// baseline (7186.852 us; speedup 1.0000x reference)
//
#include <hip/hip_runtime.h>
#include <math.h>

#define NB 8
#define NC 684
#define NH 16
#define NW 64
#define NHW 1024
#define NHID 256
#define NAD 512
#define NV 111
#define NT 36
#define NBLK 264

__device__ __forceinline__ float wred_sum(float v){
  #pragma unroll
  for (int o = 32; o > 0; o >>= 1) v += __shfl_xor(v, o, 64);
  return v;
}
__device__ __forceinline__ float wred_max(float v){
  #pragma unroll
  for (int o = 32; o > 0; o >>= 1) v = fmaxf(v, __shfl_xor(v, o, 64));
  return v;
}
__device__ __forceinline__ float fsig(float x){ return 1.f/(1.f + __expf(-x)); }
__device__ __forceinline__ float ftanh(float x){ float e = __expf(2.f*x); return 1.f - 2.f/(e + 1.f); }

// ---------------- P0: dmask, msum, ys/xs, idt
__global__ void k_p0(const float* __restrict__ im, float* __restrict__ dmask,
                     float* __restrict__ msum, float* __restrict__ ys, float* __restrict__ xs,
                     float* __restrict__ idt)
{
  const int tid = threadIdx.x; // 256 threads, 1 block
  for (int i = tid; i < NB*NHW; i += 256){
    int b = i >> 10, hw = i & 1023; int h = hw >> 6, w = hw & 63;
    dmask[i] = im[b*(256*1024) + (h*16)*1024 + (w*16)];
  }
  if (tid < 128) idt[tid] = expf(-(float)tid * (9.210340371976184f/128.f));
  __syncthreads();
  if (tid < 8){
    float s = 0.f;
    for (int i = 0; i < NHW; i++) s += dmask[tid*NHW + i];
    msum[tid] = s;
  }
  for (int p = tid; p < NB*NW; p += 256){
    int b = p >> 6, w = p & 63;
    float tot = 0.f;
    for (int h = 0; h < NH; h++) tot += dmask[b*NHW + h*64 + w];
    float inv = 6.283185307179586f/(tot + 1e-6f);
    float run = 0.f;
    for (int h = 0; h < NH; h++){ run += dmask[b*NHW + h*64 + w]; ys[b*NHW + h*64 + w] = run*inv; }
  }
  for (int p = tid; p < NB*NH; p += 256){
    int b = p >> 4, h = p & 15;
    float tot = 0.f;
    for (int w = 0; w < NW; w++) tot += dmask[b*NHW + h*64 + w];
    float inv = 6.283185307179586f/(tot + 1e-6f);
    float run = 0.f;
    for (int w = 0; w < NW; w++){ run += dmask[b*NHW + h*64 + w]; xs[b*NHW + h*64 + w] = run*inv; }
  }
}

// ---------------- P1: masked average
__global__ void k_avg(const float* __restrict__ cnn, const float* __restrict__ dmask,
                      const float* __restrict__ msum, float* __restrict__ avg)
{
  int gid = blockIdx.x*blockDim.x + threadIdx.x;
  int gw = gid >> 6, lane = gid & 63;
  int nw = (gridDim.x*blockDim.x) >> 6;
  for (int ow = gw; ow < NB*NC; ow += nw){
    int b = ow / NC;
    const float* base = cnn + (size_t)ow * NHW;
    const float* dm = dmask + b*NHW;
    float s = 0.f;
    for (int i = lane; i < NHW; i += 64) s += base[i]*dm[i];
    s = wred_sum(s);
    if (lane == 0) avg[ow] = s / msum[b];
  }
}

// ---------------- P2: hidden(-1) + counting_ctx
__global__ void k_init(const float* __restrict__ avg, const float* __restrict__ iW, const float* __restrict__ ib,
                       const float* __restrict__ cp, const float* __restrict__ cW, const float* __restrict__ cb,
                       float* __restrict__ hm1, float* __restrict__ cctx)
{
  int gid = blockIdx.x*blockDim.x + threadIdx.x;
  int gw = gid >> 6, lane = gid & 63;
  int nw = (gridDim.x*blockDim.x) >> 6;
  for (int ow = gw; ow < 2*NB*NHID; ow += nw){
    if (ow < NB*NHID){
      int b = ow >> 8, j = ow & 255;
      float s = 0.f;
      for (int k = lane; k < NC; k += 64) s += avg[b*NC + k]*iW[j*NC + k];
      s = wred_sum(s);
      if (lane == 0) hm1[ow] = tanhf(s + ib[j]);
    } else {
      int o = ow - NB*NHID; int b = o >> 8, j = o & 255;
      float s = 0.f;
      for (int k = lane; k < NV; k += 64) s += cp[b*NV + k]*cW[j*NV + k];
      s = wred_sum(s);
      if (lane == 0) cctx[o] = s + cb[j];
    }
  }
}

// ---------------- P3: trans GEMM (128x64 tile, 8x4/thread) + bias + sine pos-emb
__global__ __launch_bounds__(256) void k_trans(const float* __restrict__ cnn, const float* __restrict__ ew,
     const float* __restrict__ eb, const float* __restrict__ ys, const float* __restrict__ xs,
     const float* __restrict__ idt, float* __restrict__ trans)
{
  const int m0 = blockIdx.x << 7;
  const int n0 = blockIdx.y << 6;
  const int b  = m0 >> 10;
  const int hw0 = m0 & 1023;
  __shared__ float As[16][132];
  __shared__ float Bs[16][68];
  const int tid = threadIdx.x;
  const int tx = tid & 15, ty = tid >> 4;
  float acc[8][4];
  #pragma unroll
  for (int i=0;i<8;i++)
    #pragma unroll
    for (int j=0;j<4;j++) acc[i][j]=0.f;
  for (int c0 = 0; c0 < NC; c0 += 16){
    #pragma unroll
    for (int u = 0; u < 8; u++){
      int idx = tid + (u<<8);
      int cc = idx >> 7, mm = idx & 127;
      int c = c0 + cc;
      As[cc][mm] = (c < NC) ? cnn[((size_t)b*NC + c)*NHW + hw0 + mm] : 0.f;
    }
    #pragma unroll
    for (int u = 0; u < 4; u++){
      int idx = tid + (u<<8);
      int nn = idx >> 4, cc = idx & 15;
      int c = c0 + cc;
      Bs[cc][nn] = (c < NC) ? ew[(size_t)(n0 + nn)*NC + c] : 0.f;
    }
    __syncthreads();
    #pragma unroll
    for (int k = 0; k < 16; k++){
      float4 a0 = *(const float4*)&As[k][ty*8];
      float4 a1 = *(const float4*)&As[k][ty*8+4];
      float4 bb = *(const float4*)&Bs[k][tx*4];
      float a[8] = {a0.x,a0.y,a0.z,a0.w,a1.x,a1.y,a1.z,a1.w};
      #pragma unroll
      for (int i=0;i<8;i++){
        acc[i][0] += a[i]*bb.x; acc[i][1] += a[i]*bb.y;
        acc[i][2] += a[i]*bb.z; acc[i][3] += a[i]*bb.w;
      }
    }
    __syncthreads();
  }
  const int dbase = n0 + tx*4;
  float ebv[4], idtv[4]; int codd[4];
  #pragma unroll
  for (int j = 0; j < 4; j++){
    int d = dbase + j;
    ebv[j] = eb[d];
    idtv[j] = (d < 256) ? idt[d>>1] : idt[(d-256)>>1];
    codd[j] = d & 1;
  }
  const int usex = dbase >= 256;
  #pragma unroll
  for (int i = 0; i < 8; i++){
    int hw = hw0 + ty*8 + i;
    float base = usex ? xs[(b<<10) + hw] : ys[(b<<10) + hw];
    float o[4];
    #pragma unroll
    for (int j = 0; j < 4; j++){
      float arg = base*idtv[j];
      float pe = codd[j] ? cosf(arg) : sinf(arg);
      o[j] = acc[i][j] + ebv[j] + pe;
    }
    *(float4*)(trans + ((size_t)(b<<10) + hw)*NAD + dbase) = make_float4(o[0],o[1],o[2],o[3]);
  }
}

// ---------------- P4: gi + embw for all steps
__global__ void k_pre(const int* __restrict__ labels, const float* __restrict__ emb,
    const float* __restrict__ wih, const float* __restrict__ bih,
    const float* __restrict__ ewW, const float* __restrict__ ewb,
    float* __restrict__ gi, float* __restrict__ embw)
{
  int gid = blockIdx.x*blockDim.x + threadIdx.x;
  int gw = gid >> 6, lane = gid & 63;
  int nw = (gridDim.x*blockDim.x) >> 6;
  const int NGI = NT*NB*768;
  const int NEW_ = NT*NB*256;
  for (int ow = gw; ow < NGI + NEW_; ow += nw){
    if (ow < NGI){
      int i = ow % 768; int tb = ow / 768; int b = tb & 7, t = tb >> 3;
      int word = (t == 0) ? 1 : labels[b*NT + t - 1];
      const float* er = emb + (size_t)word*256;
      float s = 0.f;
      for (int k = lane; k < 256; k += 64) s += er[k]*wih[(size_t)i*256 + k];
      s = wred_sum(s);
      if (lane == 0) gi[ow] = s + bih[i];
    } else {
      int o = ow - NGI; int j = o & 255; int tb = o >> 8; int b = tb & 7, t = tb >> 3;
      int word = (t == 0) ? 1 : labels[b*NT + t - 1];
      const float* er = emb + (size_t)word*256;
      float s = 0.f;
      for (int k = lane; k < 256; k += 64) s += er[k]*ewW[(size_t)j*256 + k];
      s = wred_sum(s);
      if (lane == 0) embw[o] = s + ewb[j];
    }
  }
}

// ---------------- P5: Mt[tap][d]
__global__ void k_mt(const float* __restrict__ aw, const float* __restrict__ acw, float* __restrict__ Mt)
{
  __shared__ float col[512];
  int t = blockIdx.x; int tid = threadIdx.x;
  for (int c = tid; c < 512; c += 256) col[c] = acw[(size_t)c*121 + t];
  __syncthreads();
  for (int d = tid; d < 512; d += 256){
    float s = 0.f;
    const float4* r4 = (const float4*)(aw + (size_t)d*512);
    for (int k = 0; k < 128; k++){
      float4 w = r4[k];
      s += col[k*4+0]*w.x + col[k*4+1]*w.y + col[k*4+2]*w.z + col[k*4+3]*w.w;
    }
    Mt[t*512 + d] = s;
  }
}

// ---------------- P6: SO = oW@sW; CB
__global__ __launch_bounds__(256) void k_so(const float* __restrict__ sW, const float* __restrict__ oW,
    const float* __restrict__ sb, const float* __restrict__ cxb, const float* __restrict__ cctx,
    const float* __restrict__ ob, float* __restrict__ SO, float* __restrict__ CB)
{
  const int v = blockIdx.x; const int tid = threadIdx.x;
  float acc = 0.f;
  for (int j = 0; j < 256; j++) acc += sW[(size_t)j*256 + tid] * oW[(size_t)v*256 + j];
  SO[(size_t)v*256 + tid] = acc;
  if (tid < 8){
    float s = ob[v];
    for (int j = 0; j < 256; j++) s += (sb[j] + cxb[j] + cctx[tid*256 + j]) * oW[(size_t)v*256 + j];
    CB[tid*NV + v] = s;
  }
}

// ---------------- P7: embwO
__global__ __launch_bounds__(512) void k_embwO(const float* __restrict__ embw, const float* __restrict__ oW,
                                               float* __restrict__ embwO)
{
  const int v = blockIdx.x; const int tid = threadIdx.x;
  const int lane = tid & 63, wid = tid >> 6;
  __shared__ float ows[256];
  if (tid < 256) ows[tid] = oW[(size_t)v*256 + tid];
  __syncthreads();
  for (int tb = wid; tb < NT*NB; tb += 8){
    float acc = 0.f;
    #pragma unroll
    for (int u = 0; u < 4; u++){ int j = lane + (u<<6); acc += embw[(size_t)tb*256 + j]*ows[j]; }
    acc = wred_sum(acc);
    if (lane == 0) embwO[tb*NV + v] = acc;
  }
}

// ---------------- P8: CO[c][v]
__global__ __launch_bounds__(256) void k_co(const float* __restrict__ cxW, const float* __restrict__ oW,
                                            float* __restrict__ CO)
{
  const int c = blockIdx.x*256 + threadIdx.x;
  const int v = blockIdx.y;
  if (c >= NC) return;
  float acc = 0.f;
  for (int j = 0; j < 256; j++) acc += cxW[(size_t)j*NC + c] * oW[(size_t)v*256 + j];
  CO[(size_t)c*128 + v] = acc;
  if (v == 0){
    for (int vv = NV; vv < 128; vv++) CO[(size_t)c*128 + vv] = 0.f;
  }
}

// ---------------- P9: PO GEMM (64x64 tile, 4x4/thread)
__global__ __launch_bounds__(256) void k_gemm_PO(const float* __restrict__ cnn, const float* __restrict__ CO,
                                                 float* __restrict__ PO)
{
  const int m0 = blockIdx.x << 6;
  const int n0 = blockIdx.y << 6;
  const int b  = blockIdx.z;
  __shared__ float As[32][64];
  __shared__ float Bs[32][65];
  const int tid = threadIdx.x;
  const int tx = tid & 15, ty = tid >> 4;
  float acc[4][4];
  #pragma unroll
  for (int i=0;i<4;i++)
    #pragma unroll
    for (int j=0;j<4;j++) acc[i][j]=0.f;
  for (int c0 = 0; c0 < NC; c0 += 32){
    int kc = NC - c0; if (kc > 32) kc = 32;
    for (int idx = tid; idx < 32*64; idx += 256){
      int cc = idx >> 6, mm = idx & 63;
      As[cc][mm] = (cc < kc) ? cnn[((size_t)b*NC + c0 + cc)*NHW + m0 + mm] : 0.f;
    }
    for (int idx = tid; idx < 32*64; idx += 256){
      int cc = idx >> 6, nn = idx & 63;
      Bs[cc][nn] = (cc < kc) ? CO[(size_t)(c0 + cc)*128 + n0 + nn] : 0.f;
    }
    __syncthreads();
    #pragma unroll
    for (int k = 0; k < 32; k++){
      float a0 = As[k][tx*4+0], a1 = As[k][tx*4+1], a2 = As[k][tx*4+2], a3 = As[k][tx*4+3];
      float b0 = Bs[k][ty*4+0], b1 = Bs[k][ty*4+1], b2 = Bs[k][ty*4+2], b3 = Bs[k][ty*4+3];
      acc[0][0]+=a0*b0; acc[0][1]+=a0*b1; acc[0][2]+=a0*b2; acc[0][3]+=a0*b3;
      acc[1][0]+=a1*b0; acc[1][1]+=a1*b1; acc[1][2]+=a1*b2; acc[1][3]+=a1*b3;
      acc[2][0]+=a2*b0; acc[2][1]+=a2*b1; acc[2][2]+=a2*b2; acc[2][3]+=a2*b3;
      acc[3][0]+=a3*b0; acc[3][1]+=a3*b1; acc[3][2]+=a3*b2; acc[3][3]+=a3*b3;
    }
    __syncthreads();
  }
  #pragma unroll
  for (int j = 0; j < 4; j++){
    int v = n0 + ty*4 + j;
    float* dst = PO + (((size_t)b*128 + v)<<10) + m0 + tx*4;
    *(float4*)dst = make_float4(acc[0][j],acc[1][j],acc[2][j],acc[3][j]);
  }
}

// ---------------- gru slice helper — prologue only
__device__ __forceinline__ void gru_slice(const float* __restrict__ hs, const float* __restrict__ whh,
    const float* __restrict__ bhh, const float* __restrict__ gg, float* __restrict__ hdst,
    int r, int wid, int lane)
{
  #pragma unroll 1
  for (int jj = 0; jj < 8; jj++){
    int j = (r<<6) + (wid<<3) + jj;
    float sr = 0.f, sz = 0.f, sn = 0.f;
    #pragma unroll
    for (int u = 0; u < 4; u++){
      int k = lane + (u<<6);
      float hv = hs[k];
      sr += hv * whh[(size_t)j*256 + k];
      sz += hv * whh[(size_t)(j+256)*256 + k];
      sn += hv * whh[(size_t)(j+512)*256 + k];
    }
    sr = wred_sum(sr); sz = wred_sum(sz); sn = wred_sum(sn);
    if (lane == 0){
      float rr = 1.f/(1.f + expf(-(gg[j] + sr + bhh[j])));
      float zz = 1.f/(1.f + expf(-(gg[j+256] + sz + bhh[j+256])));
      float nn = tanhf(gg[j+512] + rr*(sn + bhh[j+512]));
      hdst[j] = (1.f - zz)*nn + zz*hs[j];
    }
  }
}

// ---------------- P10: initial GRU: hm1 -> h(0) (hbuf3 slot 0)
__global__ __launch_bounds__(512) void k_gq0(const float* __restrict__ hm1, const float* __restrict__ whh,
    const float* __restrict__ bhh, const float* __restrict__ gi, float* __restrict__ hbuf3)
{
  const int r = blockIdx.x, b = blockIdx.y;
  const int tid = threadIdx.x, lane = tid & 63, wid = tid >> 6;
  __shared__ float hs[256];
  if (tid < 256) hs[tid] = hm1[(b<<8) + tid];
  __syncthreads();
  gru_slice(hs, whh, bhh, gi + (size_t)b*768, hbuf3 + (b<<8), r, wid, lane);
}

// ---------------- P11: query(0) into qbuf slot 0
__global__ __launch_bounds__(512) void k_query0(const float* __restrict__ hbuf3, const float* __restrict__ ahW,
    const float* __restrict__ ahb, float* __restrict__ qbuf)
{
  const int b = blockIdx.x >> 3, dc = blockIdx.x & 7;
  const int tid = threadIdx.x, lane = tid & 63, wid = tid >> 6;
  __shared__ float hs[256];
  if (tid < 256) hs[tid] = hbuf3[(b<<8) + tid];
  __syncthreads();
  #pragma unroll 1
  for (int i = 0; i < 8; i++){
    int d = (dc<<6) + (wid<<3) + i;
    float acc = 0.f;
    #pragma unroll
    for (int u = 0; u < 4; u++){ int k = lane + (u<<6); acc += hs[k]*ahW[(size_t)d*256 + k]; }
    acc = wred_sum(acc);
    if (lane == 0) qbuf[(b<<9) + d] = acc + ahb[d];
  }
}

// ---------------- P12: weight transposes
__global__ void k_tr(const float* __restrict__ whh, const float* __restrict__ ahW,
                     float* __restrict__ whhT, float* __restrict__ ahWT)
{
  int i = blockIdx.x*256 + threadIdx.x;
  int stride = gridDim.x*256;
  for (int x = i; x < 768*256; x += stride){
    int g = x >> 16, k = (x >> 8) & 255, j = x & 255;
    whhT[x] = whh[(size_t)((g<<8)+j)*256 + k];
  }
  for (int x = i; x < 256*512; x += stride){
    int k = x >> 9, d = x & 511;
    ahWT[x] = ahW[(size_t)(d<<8) + k];
  }
}

// ================= persistent main loop =================
// blocks 0..255 (b=gid>>5, seg=gid&31, h=seg>>1, w0=(seg&1)<<5):
//   iter i: [i>0] softmax(e(i-1)) -> al; as += alpha-halo (LDS-resident A); prob(i-1) on waves 0..3
//           [i<36] stencil(as,Mt)+tanh -> e(i)
// blocks 256..263 (b): [i<35] gru h(i+1) (hbuf3 slot (i+1)%3) + query q(i+1) (qbuf parity)
// barrier per iter: monotonic 8-sharded counter, s_sleep(32) polling.
__global__ __launch_bounds__(512, 4) void k_main(
  const float* __restrict__ dmask, const float* __restrict__ Mt,
  const float* __restrict__ trans, float* __restrict__ qbuf,
  const float* __restrict__ acvW, const float* __restrict__ acvb,
  const float* __restrict__ PO, const float* __restrict__ SO,
  const float* __restrict__ CB, const float* __restrict__ embwO,
  const float* __restrict__ gi, const float* __restrict__ whhT,
  const float* __restrict__ bhh, const float* __restrict__ ahWT,
  const float* __restrict__ ahb, float* __restrict__ hbuf3,
  float* __restrict__ ebuf, float* __restrict__ out,
  unsigned* __restrict__ cnt)
{
  const int gid = blockIdx.x, tid = threadIdx.x;
  const int lane = tid & 63, wv = tid >> 6;
  __shared__ float eo[32][512];
  __shared__ float al[1024];
  __shared__ float as[11][42];
  __shared__ float hs[256], hn[256];
  __shared__ float red[18];

  const bool isE = (gid < 256);
  const int b = isE ? (gid >> 5) : (gid - 256);
  const int seg = gid & 31, h = seg >> 1, w0 = (seg & 1) << 5;

  float dm0 = 0.f, dm1 = 0.f, wav = 0.f, acb0 = 0.f;
  if (isE){
    dm0 = dmask[(b<<10) + tid]; dm1 = dmask[(b<<10) + 512 + tid];
    wav = acvW[tid]; acb0 = acvb[0];
    for (int idx = tid; idx < 462; idx += 512){
      int r = idx/42, c = idx - r*42;
      as[r][c] = 0.f;
    }
  }
  __syncthreads();

  #pragma unroll 1
  for (int i = 0; i <= NT; i++){
    if (isE){
      if (i > 0){
        // ---- softmax(e(i-1)) -> al
        const float* ep = ebuf + (((i-1)&1)<<13) + (b<<10);
        float e0 = ep[tid], e1 = ep[512+tid];
        float m = wred_max(fmaxf(e0, e1));
        if (lane == 0) red[wv] = m;
        __syncthreads();
        if (tid == 0){
          float g = red[0];
          #pragma unroll
          for (int k = 1; k < 8; k++) g = fmaxf(g, red[k]);
          red[16] = g;
        }
        __syncthreads();
        float g = red[16];
        float x0 = __expf(e0 - g)*dm0, x1 = __expf(e1 - g)*dm1;
        float s = wred_sum(x0 + x1);
        if (lane == 0) red[wv] = s;
        __syncthreads();
        if (tid == 0){
          float ss = 0.f;
          #pragma unroll
          for (int k = 0; k < 8; k++) ss += red[k];
          red[17] = ss;
        }
        __syncthreads();
        float inv = 1.f/(red[17] + 1e-10f);
        al[tid] = x0*inv; al[512+tid] = x1*inv;
        __syncthreads();
        // ---- halo A update (LDS-resident)
        for (int idx = tid; idx < 462; idx += 512){
          int r = idx/42, c = idx - r*42;
          int hi = h + r - 5, wi = w0 + c - 5;
          if ((unsigned)hi < 16u && (unsigned)wi < 64u)
            as[r][c] += al[(hi<<6) + wi];
        }
        // ---- prob(i-1): waves 0..3, v = seg + 32*wv
        if (wv < 4){
          int v = seg + (wv<<5);
          if (v < NV){
            const float* POr = PO + (((size_t)b*128 + v)<<10);
            const float* hr = hbuf3 + ((i-1)%3)*2048 + (b<<8);
            const float* SOr = SO + (size_t)v*256;
            float a2 = 0.f;
            #pragma unroll
            for (int u = 0; u < 16; u++){ int p = lane + (u<<6); a2 += al[p]*POr[p]; }
            #pragma unroll
            for (int u = 0; u < 4; u++){ int k = lane + (u<<6); a2 += hr[k]*SOr[k]; }
            a2 = wred_sum(a2);
            if (lane == 0)
              out[((size_t)b*NT + (i-1))*NV + v] = a2 + CB[b*NV + v] + embwO[(((i-1)<<3)+b)*NV + v];
          }
        }
        __syncthreads();
      }
      if (i < NT){
        // ---- stencil: thread owns d=tid, acc over 32 w
        float accw[32];
        #pragma unroll
        for (int w = 0; w < 32; w++) accw[w] = 0.f;
        #pragma unroll 1
        for (int ki = 0; ki < 11; ki++){
          float row[42];
          #pragma unroll
          for (int j = 0; j < 42; j++) row[j] = as[ki][j];
          float mx = 0.f;
          #pragma unroll
          for (int j = 0; j < 42; j++) mx = fmaxf(mx, fabsf(row[j]));
          if (mx != 0.f){
            const float* mrow = Mt + ki*11*512 + tid;
            #pragma unroll
            for (int kj = 0; kj < 11; kj++){
              float m = mrow[kj*512];
              #pragma unroll
              for (int w = 0; w < 32; w++) accw[w] += row[kj + w]*m;
            }
          }
        }
        // ---- tail: tanh -> eo LDS transpose -> wave-parallel reduce
        float q = qbuf[((i&1)<<12) + (b<<9) + tid];
        const float* tbase = trans + (((size_t)(b<<10) + (h<<6) + w0))*NAD + tid;
        #pragma unroll 1
        for (int w = 0; w < 32; w++)
          eo[w][tid] = wav * ftanh(q + tbase[(size_t)w*NAD] + accw[w]);
        __syncthreads();
        float* ecur = ebuf + ((i&1)<<13) + (b<<10) + (h<<6) + w0;
        #pragma unroll
        for (int k = 0; k < 4; k++){
          int w = (wv<<2) + k;
          float sum = 0.f;
          #pragma unroll
          for (int u = 0; u < 8; u++) sum += eo[w][lane + (u<<6)];
          sum = wred_sum(sum);
          if (lane == 0) ecur[w] = sum + acb0;
        }
      }
    } else {
      // ---- aux: gru h(i+1), query q(i+1)
      if (i < NT-1){
        if (tid < 256) hs[tid] = hbuf3[(i%3)*2048 + (b<<8) + tid];
        __syncthreads();
        if (tid < 256){
          const int j = tid;
          float sr = 0.f, sz = 0.f, sn = 0.f;
          #pragma unroll 4
          for (int k = 0; k < 256; k++){
            float hv = hs[k];
            sr += hv * whhT[(k<<8) + j];
            sz += hv * whhT[((256+k)<<8) + j];
            sn += hv * whhT[((512+k)<<8) + j];
          }
          const float* gg = gi + (size_t)(((i+1)<<3) + b)*768;
          float r = fsig(gg[j] + sr + bhh[j]);
          float z = fsig(gg[j+256] + sz + bhh[j+256]);
          float n = ftanh(gg[j+512] + r*(sn + bhh[j+512]));
          float hv2 = (1.f - z)*n + z*hs[j];
          hn[j] = hv2;
          hbuf3[((i+1)%3)*2048 + (b<<8) + j] = hv2;
        }
        __syncthreads();
        {
          const int d = tid;
          float s2 = 0.f;
          #pragma unroll 4
          for (int k = 0; k < 256; k++) s2 += hn[k]*ahWT[(k<<9) + d];
          qbuf[(((i+1)&1)<<12) + (b<<9) + d] = s2 + ahb[d];
        }
      }
    }
    // ---- grid barrier (skip after final iteration)
    if (i < NT){
      __syncthreads();
      if (tid == 0){
        __threadfence();
        __hip_atomic_fetch_add(&cnt[(gid & 7)*32], 1u, __ATOMIC_ACQ_REL, __HIP_MEMORY_SCOPE_AGENT);
        unsigned target = (unsigned)NBLK*(unsigned)(i+1);
        for (;;){
          unsigned s = 0;
          #pragma unroll
          for (int k = 0; k < 8; k++)
            s += __hip_atomic_load(&cnt[k*32], __ATOMIC_ACQUIRE, __HIP_MEMORY_SCOPE_AGENT);
          if (s >= target) break;
          __builtin_amdgcn_s_sleep(32);
        }
      }
      __syncthreads();
    }
  }
}

extern "C" void kernel_launch(void* const* d_in, const int* in_sizes, int n_in,
                              void* d_out, int out_size, void* d_ws, size_t ws_size,
                              hipStream_t stream)
{
  const float* cnn  = (const float*)d_in[0];
  const float* cp   = (const float*)d_in[1];
  const float* im   = (const float*)d_in[2];
  const float* iW   = (const float*)d_in[3];
  const float* ib   = (const float*)d_in[4];
  const float* emb  = (const float*)d_in[5];
  const float* wih  = (const float*)d_in[6];
  const float* whh  = (const float*)d_in[7];
  const float* bih  = (const float*)d_in[8];
  const float* bhh  = (const float*)d_in[9];
  const float* ahW  = (const float*)d_in[10];
  const float* ahb  = (const float*)d_in[11];
  const float* acw  = (const float*)d_in[12];
  const float* awW  = (const float*)d_in[13];
  const float* acvW = (const float*)d_in[14];
  const float* acvb = (const float*)d_in[15];
  const float* ecw  = (const float*)d_in[16];
  const float* ecb  = (const float*)d_in[17];
  const float* sW   = (const float*)d_in[18];
  const float* sb   = (const float*)d_in[19];
  const float* ewW  = (const float*)d_in[20];
  const float* ewb  = (const float*)d_in[21];
  const float* cxW  = (const float*)d_in[22];
  const float* cxb  = (const float*)d_in[23];
  const float* cW   = (const float*)d_in[24];
  const float* cb   = (const float*)d_in[25];
  const float* oW   = (const float*)d_in[26];
  const float* ob   = (const float*)d_in[27];
  const int*   lab  = (const int*)d_in[28];
  float* out = (float*)d_out;
  float* ws = (float*)d_ws;

  float* dmask  = ws + 0;        // 8192
  float* ys     = ws + 8192;     // 8192
  float* xs     = ws + 16384;    // 8192
  float* idt    = ws + 24576;    // 128
  float* msum   = ws + 24704;    // 16
  float* avg    = ws + 24720;    // 5472
  float* cctx   = ws + 30192;    // 2048
  float* hm1    = ws + 32240;    // 2048
  float* hbuf3  = ws + 34288;    // 6144 (3 x 8 x 256)
  float* qbuf   = ws + 40432;    // 8192 (2 x 8 x 512)
  float* ebuf   = ws + 48624;    // 16384
  float* gi     = ws + 65008;    // 221184
  float* embw   = ws + 286192;   // 73728
  float* Mt     = ws + 359920;   // 61952
  float* SO     = ws + 421872;   // 28416
  float* CB     = ws + 450288;   // 896
  float* embwO  = ws + 451184;   // 32000
  float* CO     = ws + 483184;   // 87552
  float* whhT   = ws + 570736;   // 196608
  float* ahWT   = ws + 767344;   // 131072
  unsigned* cnt = (unsigned*)(ws + 898416); // 256 u32 (8 shards x 32)
  float* trans  = ws + 898672;   // 4194304
  float* PO     = ws + 5092976;  // 4194304   (total ~37.2 MB)

  hipMemsetAsync((void*)cnt, 0, 256*sizeof(unsigned), stream);

  k_p0<<<1, 256, 0, stream>>>(im, dmask, msum, ys, xs, idt);
  k_avg<<<456, 256, 0, stream>>>(cnn, dmask, msum, avg);
  k_init<<<256, 256, 0, stream>>>(avg, iW, ib, cp, cW, cb, hm1, cctx);
  k_pre<<<1024, 256, 0, stream>>>(lab, emb, wih, bih, ewW, ewb, gi, embw);
  k_trans<<<dim3(64, 8), 256, 0, stream>>>(cnn, ecw, ecb, ys, xs, idt, trans);
  k_mt<<<121, 256, 0, stream>>>(awW, acw, Mt);
  k_so<<<NV, 256, 0, stream>>>(sW, oW, sb, cxb, cctx, ob, SO, CB);
  k_embwO<<<NV, 512, 0, stream>>>(embw, oW, embwO);
  k_co<<<dim3(3, NV), 256, 0, stream>>>(cxW, oW, CO);
  k_gemm_PO<<<dim3(16, 2, 8), 256, 0, stream>>>(cnn, CO, PO);
  k_tr<<<128, 256, 0, stream>>>(whh, ahW, whhT, ahWT);
  k_gq0<<<dim3(4, 8), 512, 0, stream>>>(hm1, whh, bhh, gi, hbuf3);
  k_query0<<<64, 512, 0, stream>>>(hbuf3, ahW, ahb, qbuf);

  k_main<<<NBLK, 512, 0, stream>>>(dmask, Mt, trans, qbuf, acvW, acvb, PO, SO, CB, embwO,
                                   gi, whhT, bhh, ahWT, ahb, hbuf3, ebuf, out, cnt);
}

// Round 8
// 2161.175 us; speedup vs baseline: 3.3254x; 3.3254x over previous
//
#include <hip/hip_runtime.h>
#include <math.h>

#define NB 8
#define NC 684
#define NH 16
#define NW 64
#define NHW 1024
#define NHID 256
#define NAD 512
#define NV 111
#define NT 36

__device__ __forceinline__ float wred_sum(float v){
  #pragma unroll
  for (int o = 32; o > 0; o >>= 1) v += __shfl_xor(v, o, 64);
  return v;
}
__device__ __forceinline__ float wred_max(float v){
  #pragma unroll
  for (int o = 32; o > 0; o >>= 1) v = fmaxf(v, __shfl_xor(v, o, 64));
  return v;
}
__device__ __forceinline__ float fsig(float x){ return 1.f/(1.f + __expf(-x)); }
__device__ __forceinline__ float ftanh(float x){ float e = __expf(2.f*x); return 1.f - 2.f/(e + 1.f); }

// ---------------- P0: dmask, msum, ys/xs, idt, zero abuf[0]
__global__ void k_p0(const float* __restrict__ im, float* __restrict__ dmask,
                     float* __restrict__ msum, float* __restrict__ ys, float* __restrict__ xs,
                     float* __restrict__ idt, float* __restrict__ abuf)
{
  const int tid = threadIdx.x; // 256 threads, 1 block
  for (int i = tid; i < NB*NHW; i += 256){
    int b = i >> 10, hw = i & 1023; int h = hw >> 6, w = hw & 63;
    dmask[i] = im[b*(256*1024) + (h*16)*1024 + (w*16)];
    abuf[i] = 0.f;
  }
  if (tid < 128) idt[tid] = expf(-(float)tid * (9.210340371976184f/128.f));
  __syncthreads();
  if (tid < 8){
    float s = 0.f;
    for (int i = 0; i < NHW; i++) s += dmask[tid*NHW + i];
    msum[tid] = s;
  }
  for (int p = tid; p < NB*NW; p += 256){
    int b = p >> 6, w = p & 63;
    float tot = 0.f;
    for (int h = 0; h < NH; h++) tot += dmask[b*NHW + h*64 + w];
    float inv = 6.283185307179586f/(tot + 1e-6f);
    float run = 0.f;
    for (int h = 0; h < NH; h++){ run += dmask[b*NHW + h*64 + w]; ys[b*NHW + h*64 + w] = run*inv; }
  }
  for (int p = tid; p < NB*NH; p += 256){
    int b = p >> 4, h = p & 15;
    float tot = 0.f;
    for (int w = 0; w < NW; w++) tot += dmask[b*NHW + h*64 + w];
    float inv = 6.283185307179586f/(tot + 1e-6f);
    float run = 0.f;
    for (int w = 0; w < NW; w++){ run += dmask[b*NHW + h*64 + w]; xs[b*NHW + h*64 + w] = run*inv; }
  }
}

// ---------------- P1: masked average
__global__ void k_avg(const float* __restrict__ cnn, const float* __restrict__ dmask,
                      const float* __restrict__ msum, float* __restrict__ avg)
{
  int gid = blockIdx.x*blockDim.x + threadIdx.x;
  int gw = gid >> 6, lane = gid & 63;
  int nw = (gridDim.x*blockDim.x) >> 6;
  for (int ow = gw; ow < NB*NC; ow += nw){
    int b = ow / NC;
    const float* base = cnn + (size_t)ow * NHW;
    const float* dm = dmask + b*NHW;
    float s = 0.f;
    for (int i = lane; i < NHW; i += 64) s += base[i]*dm[i];
    s = wred_sum(s);
    if (lane == 0) avg[ow] = s / msum[b];
  }
}

// ---------------- P2: hidden(-1) + counting_ctx
__global__ void k_init(const float* __restrict__ avg, const float* __restrict__ iW, const float* __restrict__ ib,
                       const float* __restrict__ cp, const float* __restrict__ cW, const float* __restrict__ cb,
                       float* __restrict__ hm1, float* __restrict__ cctx)
{
  int gid = blockIdx.x*blockDim.x + threadIdx.x;
  int gw = gid >> 6, lane = gid & 63;
  int nw = (gridDim.x*blockDim.x) >> 6;
  for (int ow = gw; ow < 2*NB*NHID; ow += nw){
    if (ow < NB*NHID){
      int b = ow >> 8, j = ow & 255;
      float s = 0.f;
      for (int k = lane; k < NC; k += 64) s += avg[b*NC + k]*iW[j*NC + k];
      s = wred_sum(s);
      if (lane == 0) hm1[ow] = tanhf(s + ib[j]);
    } else {
      int o = ow - NB*NHID; int b = o >> 8, j = o & 255;
      float s = 0.f;
      for (int k = lane; k < NV; k += 64) s += cp[b*NV + k]*cW[j*NV + k];
      s = wred_sum(s);
      if (lane == 0) cctx[o] = s + cb[j];
    }
  }
}

// ---------------- P3: trans GEMM (128x64 tile, 8x4/thread) + bias + sine pos-emb
__global__ __launch_bounds__(256) void k_trans(const float* __restrict__ cnn, const float* __restrict__ ew,
     const float* __restrict__ eb, const float* __restrict__ ys, const float* __restrict__ xs,
     const float* __restrict__ idt, float* __restrict__ trans)
{
  const int m0 = blockIdx.x << 7;
  const int n0 = blockIdx.y << 6;
  const int b  = m0 >> 10;
  const int hw0 = m0 & 1023;
  __shared__ float As[16][132];
  __shared__ float Bs[16][68];
  const int tid = threadIdx.x;
  const int tx = tid & 15, ty = tid >> 4;
  float acc[8][4];
  #pragma unroll
  for (int i=0;i<8;i++)
    #pragma unroll
    for (int j=0;j<4;j++) acc[i][j]=0.f;
  for (int c0 = 0; c0 < NC; c0 += 16){
    #pragma unroll
    for (int u = 0; u < 8; u++){
      int idx = tid + (u<<8);
      int cc = idx >> 7, mm = idx & 127;
      int c = c0 + cc;
      As[cc][mm] = (c < NC) ? cnn[((size_t)b*NC + c)*NHW + hw0 + mm] : 0.f;
    }
    #pragma unroll
    for (int u = 0; u < 4; u++){
      int idx = tid + (u<<8);
      int nn = idx >> 4, cc = idx & 15;
      int c = c0 + cc;
      Bs[cc][nn] = (c < NC) ? ew[(size_t)(n0 + nn)*NC + c] : 0.f;
    }
    __syncthreads();
    #pragma unroll
    for (int k = 0; k < 16; k++){
      float4 a0 = *(const float4*)&As[k][ty*8];
      float4 a1 = *(const float4*)&As[k][ty*8+4];
      float4 bb = *(const float4*)&Bs[k][tx*4];
      float a[8] = {a0.x,a0.y,a0.z,a0.w,a1.x,a1.y,a1.z,a1.w};
      #pragma unroll
      for (int i=0;i<8;i++){
        acc[i][0] += a[i]*bb.x; acc[i][1] += a[i]*bb.y;
        acc[i][2] += a[i]*bb.z; acc[i][3] += a[i]*bb.w;
      }
    }
    __syncthreads();
  }
  const int dbase = n0 + tx*4;
  float ebv[4], idtv[4]; int codd[4];
  #pragma unroll
  for (int j = 0; j < 4; j++){
    int d = dbase + j;
    ebv[j] = eb[d];
    idtv[j] = (d < 256) ? idt[d>>1] : idt[(d-256)>>1];
    codd[j] = d & 1;
  }
  const int usex = dbase >= 256;
  #pragma unroll
  for (int i = 0; i < 8; i++){
    int hw = hw0 + ty*8 + i;
    float base = usex ? xs[(b<<10) + hw] : ys[(b<<10) + hw];
    float o[4];
    #pragma unroll
    for (int j = 0; j < 4; j++){
      float arg = base*idtv[j];
      float pe = codd[j] ? cosf(arg) : sinf(arg);
      o[j] = acc[i][j] + ebv[j] + pe;
    }
    *(float4*)(trans + ((size_t)(b<<10) + hw)*NAD + dbase) = make_float4(o[0],o[1],o[2],o[3]);
  }
}

// ---------------- P4: gi + embw for all steps
__global__ void k_pre(const int* __restrict__ labels, const float* __restrict__ emb,
    const float* __restrict__ wih, const float* __restrict__ bih,
    const float* __restrict__ ewW, const float* __restrict__ ewb,
    float* __restrict__ gi, float* __restrict__ embw)
{
  int gid = blockIdx.x*blockDim.x + threadIdx.x;
  int gw = gid >> 6, lane = gid & 63;
  int nw = (gridDim.x*blockDim.x) >> 6;
  const int NGI = NT*NB*768;
  const int NEW_ = NT*NB*256;
  for (int ow = gw; ow < NGI + NEW_; ow += nw){
    if (ow < NGI){
      int i = ow % 768; int tb = ow / 768; int b = tb & 7, t = tb >> 3;
      int word = (t == 0) ? 1 : labels[b*NT + t - 1];
      const float* er = emb + (size_t)word*256;
      float s = 0.f;
      for (int k = lane; k < 256; k += 64) s += er[k]*wih[(size_t)i*256 + k];
      s = wred_sum(s);
      if (lane == 0) gi[ow] = s + bih[i];
    } else {
      int o = ow - NGI; int j = o & 255; int tb = o >> 8; int b = tb & 7, t = tb >> 3;
      int word = (t == 0) ? 1 : labels[b*NT + t - 1];
      const float* er = emb + (size_t)word*256;
      float s = 0.f;
      for (int k = lane; k < 256; k += 64) s += er[k]*ewW[(size_t)j*256 + k];
      s = wred_sum(s);
      if (lane == 0) embw[o] = s + ewb[j];
    }
  }
}

// ---------------- P5: Mt[tap][d]
__global__ void k_mt(const float* __restrict__ aw, const float* __restrict__ acw, float* __restrict__ Mt)
{
  __shared__ float col[512];
  int t = blockIdx.x; int tid = threadIdx.x;
  for (int c = tid; c < 512; c += 256) col[c] = acw[(size_t)c*121 + t];
  __syncthreads();
  for (int d = tid; d < 512; d += 256){
    float s = 0.f;
    const float4* r4 = (const float4*)(aw + (size_t)d*512);
    for (int k = 0; k < 128; k++){
      float4 w = r4[k];
      s += col[k*4+0]*w.x + col[k*4+1]*w.y + col[k*4+2]*w.z + col[k*4+3]*w.w;
    }
    Mt[t*512 + d] = s;
  }
}

// ---------------- P6: SO = oW@sW; CB
__global__ __launch_bounds__(256) void k_so(const float* __restrict__ sW, const float* __restrict__ oW,
    const float* __restrict__ sb, const float* __restrict__ cxb, const float* __restrict__ cctx,
    const float* __restrict__ ob, float* __restrict__ SO, float* __restrict__ CB)
{
  const int v = blockIdx.x; const int tid = threadIdx.x;
  float acc = 0.f;
  for (int j = 0; j < 256; j++) acc += sW[(size_t)j*256 + tid] * oW[(size_t)v*256 + j];
  SO[(size_t)v*256 + tid] = acc;
  if (tid < 8){
    float s = ob[v];
    for (int j = 0; j < 256; j++) s += (sb[j] + cxb[j] + cctx[tid*256 + j]) * oW[(size_t)v*256 + j];
    CB[tid*NV + v] = s;
  }
}

// ---------------- P7: embwO
__global__ __launch_bounds__(512) void k_embwO(const float* __restrict__ embw, const float* __restrict__ oW,
                                               float* __restrict__ embwO)
{
  const int v = blockIdx.x; const int tid = threadIdx.x;
  const int lane = tid & 63, wid = tid >> 6;
  __shared__ float ows[256];
  if (tid < 256) ows[tid] = oW[(size_t)v*256 + tid];
  __syncthreads();
  for (int tb = wid; tb < NT*NB; tb += 8){
    float acc = 0.f;
    #pragma unroll
    for (int u = 0; u < 4; u++){ int j = lane + (u<<6); acc += embw[(size_t)tb*256 + j]*ows[j]; }
    acc = wred_sum(acc);
    if (lane == 0) embwO[tb*NV + v] = acc;
  }
}

// ---------------- P8: CO[c][v]
__global__ __launch_bounds__(256) void k_co(const float* __restrict__ cxW, const float* __restrict__ oW,
                                            float* __restrict__ CO)
{
  const int c = blockIdx.x*256 + threadIdx.x;
  const int v = blockIdx.y;
  if (c >= NC) return;
  float acc = 0.f;
  for (int j = 0; j < 256; j++) acc += cxW[(size_t)j*NC + c] * oW[(size_t)v*256 + j];
  CO[(size_t)c*128 + v] = acc;
  if (v == 0){
    for (int vv = NV; vv < 128; vv++) CO[(size_t)c*128 + vv] = 0.f;
  }
}

// ---------------- P9: PO GEMM (64x64 tile, 4x4/thread)
__global__ __launch_bounds__(256) void k_gemm_PO(const float* __restrict__ cnn, const float* __restrict__ CO,
                                                 float* __restrict__ PO)
{
  const int m0 = blockIdx.x << 6;
  const int n0 = blockIdx.y << 6;
  const int b  = blockIdx.z;
  __shared__ float As[32][64];
  __shared__ float Bs[32][65];
  const int tid = threadIdx.x;
  const int tx = tid & 15, ty = tid >> 4;
  float acc[4][4];
  #pragma unroll
  for (int i=0;i<4;i++)
    #pragma unroll
    for (int j=0;j<4;j++) acc[i][j]=0.f;
  for (int c0 = 0; c0 < NC; c0 += 32){
    int kc = NC - c0; if (kc > 32) kc = 32;
    for (int idx = tid; idx < 32*64; idx += 256){
      int cc = idx >> 6, mm = idx & 63;
      As[cc][mm] = (cc < kc) ? cnn[((size_t)b*NC + c0 + cc)*NHW + m0 + mm] : 0.f;
    }
    for (int idx = tid; idx < 32*64; idx += 256){
      int cc = idx >> 6, nn = idx & 63;
      Bs[cc][nn] = (cc < kc) ? CO[(size_t)(c0 + cc)*128 + n0 + nn] : 0.f;
    }
    __syncthreads();
    #pragma unroll
    for (int k = 0; k < 32; k++){
      float a0 = As[k][tx*4+0], a1 = As[k][tx*4+1], a2 = As[k][tx*4+2], a3 = As[k][tx*4+3];
      float b0 = Bs[k][ty*4+0], b1 = Bs[k][ty*4+1], b2 = Bs[k][ty*4+2], b3 = Bs[k][ty*4+3];
      acc[0][0]+=a0*b0; acc[0][1]+=a0*b1; acc[0][2]+=a0*b2; acc[0][3]+=a0*b3;
      acc[1][0]+=a1*b0; acc[1][1]+=a1*b1; acc[1][2]+=a1*b2; acc[1][3]+=a1*b3;
      acc[2][0]+=a2*b0; acc[2][1]+=a2*b1; acc[2][2]+=a2*b2; acc[2][3]+=a2*b3;
      acc[3][0]+=a3*b0; acc[3][1]+=a3*b1; acc[3][2]+=a3*b2; acc[3][3]+=a3*b3;
    }
    __syncthreads();
  }
  #pragma unroll
  for (int j = 0; j < 4; j++){
    int v = n0 + ty*4 + j;
    float* dst = PO + (((size_t)b*128 + v)<<10) + m0 + tx*4;
    *(float4*)dst = make_float4(acc[0][j],acc[1][j],acc[2][j],acc[3][j]);
  }
}

// ---------------- gru slice helper — prologue only
__device__ __forceinline__ void gru_slice(const float* __restrict__ hs, const float* __restrict__ whh,
    const float* __restrict__ bhh, const float* __restrict__ gg, float* __restrict__ hdst,
    int r, int wid, int lane)
{
  #pragma unroll 1
  for (int jj = 0; jj < 8; jj++){
    int j = (r<<6) + (wid<<3) + jj;
    float sr = 0.f, sz = 0.f, sn = 0.f;
    #pragma unroll
    for (int u = 0; u < 4; u++){
      int k = lane + (u<<6);
      float hv = hs[k];
      sr += hv * whh[(size_t)j*256 + k];
      sz += hv * whh[(size_t)(j+256)*256 + k];
      sn += hv * whh[(size_t)(j+512)*256 + k];
    }
    sr = wred_sum(sr); sz = wred_sum(sz); sn = wred_sum(sn);
    if (lane == 0){
      float rr = 1.f/(1.f + expf(-(gg[j] + sr + bhh[j])));
      float zz = 1.f/(1.f + expf(-(gg[j+256] + sz + bhh[j+256])));
      float nn = tanhf(gg[j+512] + rr*(sn + bhh[j+512]));
      hdst[j] = (1.f - zz)*nn + zz*hs[j];
    }
  }
}

// ---------------- P10: initial GRU: hm1 -> h(0) (hbuf3 slot 0)
__global__ __launch_bounds__(512) void k_gq0(const float* __restrict__ hm1, const float* __restrict__ whh,
    const float* __restrict__ bhh, const float* __restrict__ gi, float* __restrict__ hbuf3)
{
  const int r = blockIdx.x, b = blockIdx.y;
  const int tid = threadIdx.x, lane = tid & 63, wid = tid >> 6;
  __shared__ float hs[256];
  if (tid < 256) hs[tid] = hm1[(b<<8) + tid];
  __syncthreads();
  gru_slice(hs, whh, bhh, gi + (size_t)b*768, hbuf3 + (b<<8), r, wid, lane);
}

// ---------------- P11: query(0) into qbuf slot 0
__global__ __launch_bounds__(512) void k_query0(const float* __restrict__ hbuf3, const float* __restrict__ ahW,
    const float* __restrict__ ahb, float* __restrict__ qbuf)
{
  const int b = blockIdx.x >> 3, dc = blockIdx.x & 7;
  const int tid = threadIdx.x, lane = tid & 63, wid = tid >> 6;
  __shared__ float hs[256];
  if (tid < 256) hs[tid] = hbuf3[(b<<8) + tid];
  __syncthreads();
  #pragma unroll 1
  for (int i = 0; i < 8; i++){
    int d = (dc<<6) + (wid<<3) + i;
    float acc = 0.f;
    #pragma unroll
    for (int u = 0; u < 4; u++){ int k = lane + (u<<6); acc += hs[k]*ahW[(size_t)d*256 + k]; }
    acc = wred_sum(acc);
    if (lane == 0) qbuf[(b<<9) + d] = acc + ahb[d];
  }
}

// ---------------- P12: weight transposes
__global__ void k_tr(const float* __restrict__ whh, const float* __restrict__ ahW,
                     float* __restrict__ whhT, float* __restrict__ ahWT)
{
  int i = blockIdx.x*256 + threadIdx.x;
  int stride = gridDim.x*256;
  for (int x = i; x < 768*256; x += stride){
    int g = x >> 16, k = (x >> 8) & 255, j = x & 255;
    whhT[x] = whh[(size_t)((g<<8)+j)*256 + k];
  }
  for (int x = i; x < 256*512; x += stride){
    int k = x >> 9, d = x & 511;
    ahWT[x] = ahW[(size_t)(d<<8) + k];
  }
}

// ================= per-step kernel (one launch per t, t = 0..NT) =================
// blocks 0..255 (b=gid>>5, seg=gid&31, h=seg>>1, w0=(seg&1)<<5):
//   [t>0] softmax(e(t-1)) -> al; prob(t-1) on waves 0..3
//   [t<36] as = A(t-1)+alpha-halo; stencil(as,Mt) thread-owns-d; chunked LDS-transpose tail -> e(t)
// blocks 256..263 (b): [t>0] softmax + A(t)=A(t-1)+alpha write; [t<35] gru h(t+1) + query q(t+1)
__global__ __launch_bounds__(512) void k_step(
  const float* __restrict__ dmask, const float* __restrict__ Mt,
  const float* __restrict__ trans, float* __restrict__ qbuf,
  const float* __restrict__ acvW, const float* __restrict__ acvb,
  const float* __restrict__ PO, const float* __restrict__ SO,
  const float* __restrict__ CB, const float* __restrict__ embwO,
  const float* __restrict__ gi, const float* __restrict__ whhT,
  const float* __restrict__ bhh, const float* __restrict__ ahWT,
  const float* __restrict__ ahb, float* __restrict__ hbuf3,
  float* __restrict__ abuf, float* __restrict__ ebuf,
  float* __restrict__ out, int t)
{
  const int gid = blockIdx.x, tid = threadIdx.x;
  const int lane = tid & 63, wv = tid >> 6;
  __shared__ float eo8[8][512];
  __shared__ float al[1024];
  __shared__ float as[11][42];
  __shared__ float hs[256], hn[256];
  __shared__ float red[18];

  const float* eprev = ebuf + (((t+1)&1)<<13);
  float*       ecurb = ebuf + ((t&1)<<13);
  const float* aprev = abuf + (((t+1)&1)<<13);
  float*       acur  = abuf + ((t&1)<<13);

  if (gid < 256){
    const int b = gid >> 5, seg = gid & 31, h = seg >> 1, w0 = (seg & 1) << 5;
    if (t > 0){
      // ---- softmax(e(t-1)) -> al
      float e0 = eprev[(b<<10)+tid], e1 = eprev[(b<<10)+512+tid];
      float dm0 = dmask[(b<<10)+tid], dm1 = dmask[(b<<10)+512+tid];
      float m = wred_max(fmaxf(e0, e1));
      if (lane == 0) red[wv] = m;
      __syncthreads();
      if (tid == 0){
        float g = red[0];
        #pragma unroll
        for (int k = 1; k < 8; k++) g = fmaxf(g, red[k]);
        red[16] = g;
      }
      __syncthreads();
      float g = red[16];
      float x0 = __expf(e0 - g)*dm0, x1 = __expf(e1 - g)*dm1;
      float s = wred_sum(x0 + x1);
      if (lane == 0) red[wv] = s;
      __syncthreads();
      if (tid == 0){
        float ss = 0.f;
        #pragma unroll
        for (int k = 0; k < 8; k++) ss += red[k];
        red[17] = ss;
      }
      __syncthreads();
      float inv = 1.f/(red[17] + 1e-10f);
      al[tid] = x0*inv; al[512+tid] = x1*inv;
      __syncthreads();
      // ---- prob(t-1): waves 0..3, v = seg + 32*wv
      if (wv < 4){
        int v = seg + (wv<<5);
        if (v < NV){
          const float* POr = PO + (((size_t)b*128 + v)<<10);
          const float* hr = hbuf3 + ((t-1)%3)*2048 + (b<<8);
          const float* SOr = SO + (size_t)v*256;
          float a2 = 0.f;
          #pragma unroll
          for (int u = 0; u < 16; u++){ int p = lane + (u<<6); a2 += al[p]*POr[p]; }
          #pragma unroll
          for (int u = 0; u < 4; u++){ int k = lane + (u<<6); a2 += hr[k]*SOr[k]; }
          a2 = wred_sum(a2);
          if (lane == 0)
            out[((size_t)b*NT + (t-1))*NV + v] = a2 + CB[b*NV + v] + embwO[(((t-1)<<3)+b)*NV + v];
        }
      }
    }
    if (t < NT){
      // ---- halo: as = A(t-1) + alpha(t-1)
      for (int idx = tid; idx < 462; idx += 512){
        int r = idx/42, c = idx - r*42;
        int hi = h + r - 5, wi = w0 + c - 5;
        float v = 0.f;
        if (t > 0 && (unsigned)hi < 16u && (unsigned)wi < 64u){
          int p = (hi<<6) + wi;
          v = aprev[(b<<10)+p] + al[p];
        }
        as[r][c] = v;
      }
      __syncthreads();
      // ---- stencil: thread owns d=tid, acc over 32 w
      float accw[32];
      #pragma unroll
      for (int w = 0; w < 32; w++) accw[w] = 0.f;
      #pragma unroll 1
      for (int ki = 0; ki < 11; ki++){
        float row[42];
        #pragma unroll
        for (int j = 0; j < 42; j++) row[j] = as[ki][j];
        float mx = 0.f;
        #pragma unroll
        for (int j = 0; j < 42; j++) mx = fmaxf(mx, fabsf(row[j]));
        if (mx != 0.f){
          const float* mrow = Mt + ki*11*512 + tid;
          #pragma unroll
          for (int kj = 0; kj < 11; kj++){
            float m = mrow[kj*512];
            #pragma unroll
            for (int w = 0; w < 32; w++) accw[w] += row[kj + w]*m;
          }
        }
      }
      // ---- tail: tanh -> chunked eo8 transpose -> wave-parallel reduce
      const float wav = acvW[tid];
      const float acb0 = acvb[0];
      float q = qbuf[((t&1)<<12) + (b<<9) + tid];
      const float* tbase = trans + (((size_t)(b<<10) + (h<<6) + w0))*NAD + tid;
      float* ecur = ecurb + (b<<10) + (h<<6) + w0;
      #pragma unroll 1
      for (int chunk = 0; chunk < 4; chunk++){
        __syncthreads();
        #pragma unroll
        for (int k = 0; k < 8; k++){
          int w = (chunk<<3) + k;
          eo8[k][tid] = wav * ftanh(q + tbase[(size_t)w*NAD] + accw[w]);
        }
        __syncthreads();
        {
          float sum = 0.f;
          #pragma unroll
          for (int u = 0; u < 8; u++) sum += eo8[wv][lane + (u<<6)];
          sum = wred_sum(sum);
          if (lane == 0) ecur[(chunk<<3) + wv] = sum + acb0;
        }
      }
    }
  } else {
    // ---- aux block for batch b
    const int b = gid - 256;
    if (t > 0){
      float e0 = eprev[(b<<10)+tid], e1 = eprev[(b<<10)+512+tid];
      float dm0 = dmask[(b<<10)+tid], dm1 = dmask[(b<<10)+512+tid];
      float m = wred_max(fmaxf(e0, e1));
      if (lane == 0) red[wv] = m;
      __syncthreads();
      if (tid == 0){
        float g = red[0];
        #pragma unroll
        for (int k = 1; k < 8; k++) g = fmaxf(g, red[k]);
        red[16] = g;
      }
      __syncthreads();
      float g = red[16];
      float x0 = __expf(e0 - g)*dm0, x1 = __expf(e1 - g)*dm1;
      float s = wred_sum(x0 + x1);
      if (lane == 0) red[wv] = s;
      __syncthreads();
      if (tid == 0){
        float ss = 0.f;
        #pragma unroll
        for (int k = 0; k < 8; k++) ss += red[k];
        red[17] = ss;
      }
      __syncthreads();
      float inv = 1.f/(red[17] + 1e-10f);
      if (t < NT){
        acur[(b<<10)+tid]     = aprev[(b<<10)+tid]     + x0*inv;
        acur[(b<<10)+512+tid] = aprev[(b<<10)+512+tid] + x1*inv;
      }
    }
    if (t < NT-1){
      if (tid < 256) hs[tid] = hbuf3[(t%3)*2048 + (b<<8) + tid];
      __syncthreads();
      if (tid < 256){
        const int j = tid;
        float sr = 0.f, sz = 0.f, sn = 0.f;
        #pragma unroll 4
        for (int k = 0; k < 256; k++){
          float hv = hs[k];
          sr += hv * whhT[(k<<8) + j];
          sz += hv * whhT[((256+k)<<8) + j];
          sn += hv * whhT[((512+k)<<8) + j];
        }
        const float* gg = gi + (size_t)(((t+1)<<3) + b)*768;
        float r = fsig(gg[j] + sr + bhh[j]);
        float z = fsig(gg[j+256] + sz + bhh[j+256]);
        float n = ftanh(gg[j+512] + r*(sn + bhh[j+512]));
        float hv2 = (1.f - z)*n + z*hs[j];
        hn[j] = hv2;
        hbuf3[((t+1)%3)*2048 + (b<<8) + j] = hv2;
      }
      __syncthreads();
      {
        const int d = tid;
        float s2 = 0.f;
        #pragma unroll 4
        for (int k = 0; k < 256; k++) s2 += hn[k]*ahWT[(k<<9) + d];
        qbuf[(((t+1)&1)<<12) + (b<<9) + d] = s2 + ahb[d];
      }
    }
  }
}

extern "C" void kernel_launch(void* const* d_in, const int* in_sizes, int n_in,
                              void* d_out, int out_size, void* d_ws, size_t ws_size,
                              hipStream_t stream)
{
  const float* cnn  = (const float*)d_in[0];
  const float* cp   = (const float*)d_in[1];
  const float* im   = (const float*)d_in[2];
  const float* iW   = (const float*)d_in[3];
  const float* ib   = (const float*)d_in[4];
  const float* emb  = (const float*)d_in[5];
  const float* wih  = (const float*)d_in[6];
  const float* whh  = (const float*)d_in[7];
  const float* bih  = (const float*)d_in[8];
  const float* bhh  = (const float*)d_in[9];
  const float* ahW  = (const float*)d_in[10];
  const float* ahb  = (const float*)d_in[11];
  const float* acw  = (const float*)d_in[12];
  const float* awW  = (const float*)d_in[13];
  const float* acvW = (const float*)d_in[14];
  const float* acvb = (const float*)d_in[15];
  const float* ecw  = (const float*)d_in[16];
  const float* ecb  = (const float*)d_in[17];
  const float* sW   = (const float*)d_in[18];
  const float* sb   = (const float*)d_in[19];
  const float* ewW  = (const float*)d_in[20];
  const float* ewb  = (const float*)d_in[21];
  const float* cxW  = (const float*)d_in[22];
  const float* cxb  = (const float*)d_in[23];
  const float* cW   = (const float*)d_in[24];
  const float* cb   = (const float*)d_in[25];
  const float* oW   = (const float*)d_in[26];
  const float* ob   = (const float*)d_in[27];
  const int*   lab  = (const int*)d_in[28];
  float* out = (float*)d_out;
  float* ws = (float*)d_ws;

  float* dmask  = ws + 0;        // 8192
  float* ys     = ws + 8192;     // 8192
  float* xs     = ws + 16384;    // 8192
  float* idt    = ws + 24576;    // 128
  float* msum   = ws + 24704;    // 16
  float* avg    = ws + 24720;    // 5472
  float* cctx   = ws + 30192;    // 2048
  float* hm1    = ws + 32240;    // 2048
  float* hbuf3  = ws + 34288;    // 6144 (3 x 8 x 256)
  float* qbuf   = ws + 40432;    // 8192 (2 x 8 x 512)
  float* abuf   = ws + 48624;    // 16384 (2 x 8 x 1024)
  float* ebuf   = ws + 65008;    // 16384
  float* gi     = ws + 81392;    // 221184
  float* embw   = ws + 302576;   // 73728
  float* Mt     = ws + 376304;   // 61952
  float* SO     = ws + 438256;   // 28416
  float* CB     = ws + 466672;   // 896
  float* embwO  = ws + 467568;   // 32000
  float* CO     = ws + 499568;   // 87552
  float* whhT   = ws + 587120;   // 196608
  float* ahWT   = ws + 783728;   // 131072
  float* trans  = ws + 914800;   // 4194304
  float* PO     = ws + 5109104;  // 4194304   (total ~37.2 MB)

  k_p0<<<1, 256, 0, stream>>>(im, dmask, msum, ys, xs, idt, abuf);
  k_avg<<<456, 256, 0, stream>>>(cnn, dmask, msum, avg);
  k_init<<<256, 256, 0, stream>>>(avg, iW, ib, cp, cW, cb, hm1, cctx);
  k_pre<<<1024, 256, 0, stream>>>(lab, emb, wih, bih, ewW, ewb, gi, embw);
  k_trans<<<dim3(64, 8), 256, 0, stream>>>(cnn, ecw, ecb, ys, xs, idt, trans);
  k_mt<<<121, 256, 0, stream>>>(awW, acw, Mt);
  k_so<<<NV, 256, 0, stream>>>(sW, oW, sb, cxb, cctx, ob, SO, CB);
  k_embwO<<<NV, 512, 0, stream>>>(embw, oW, embwO);
  k_co<<<dim3(3, NV), 256, 0, stream>>>(cxW, oW, CO);
  k_gemm_PO<<<dim3(16, 2, 8), 256, 0, stream>>>(cnn, CO, PO);
  k_tr<<<128, 256, 0, stream>>>(whh, ahW, whhT, ahWT);
  k_gq0<<<dim3(4, 8), 512, 0, stream>>>(hm1, whh, bhh, gi, hbuf3);
  k_query0<<<64, 512, 0, stream>>>(hbuf3, ahW, ahb, qbuf);

  for (int t = 0; t <= NT; t++){
    k_step<<<264, 512, 0, stream>>>(dmask, Mt, trans, qbuf, acvW, acvb, PO, SO, CB, embwO,
                                    gi, whhT, bhh, ahWT, ahb, hbuf3, abuf, ebuf, out, t);
  }
}

// Round 9
// 2029.320 us; speedup vs baseline: 3.5415x; 1.0650x over previous
//
#include <hip/hip_runtime.h>
#include <hip/hip_bf16.h>
#include <math.h>

#define NB 8
#define NC 684
#define NH 16
#define NW 64
#define NHW 1024
#define NHID 256
#define NAD 512
#define NV 111
#define NT 36

__device__ __forceinline__ float wred_sum(float v){
  #pragma unroll
  for (int o = 32; o > 0; o >>= 1) v += __shfl_xor(v, o, 64);
  return v;
}
__device__ __forceinline__ float wred_max(float v){
  #pragma unroll
  for (int o = 32; o > 0; o >>= 1) v = fmaxf(v, __shfl_xor(v, o, 64));
  return v;
}
__device__ __forceinline__ float fsig(float x){ return 1.f/(1.f + __expf(-x)); }
__device__ __forceinline__ float ftanh(float x){ float e = __expf(2.f*x); return 1.f - 2.f/(e + 1.f); }

// ---------------- P0: dmask, msum, ys/xs, idt, zero abuf[0]
__global__ void k_p0(const float* __restrict__ im, float* __restrict__ dmask,
                     float* __restrict__ msum, float* __restrict__ ys, float* __restrict__ xs,
                     float* __restrict__ idt, float* __restrict__ abuf)
{
  const int tid = threadIdx.x; // 256 threads, 1 block
  for (int i = tid; i < NB*NHW; i += 256){
    int b = i >> 10, hw = i & 1023; int h = hw >> 6, w = hw & 63;
    dmask[i] = im[b*(256*1024) + (h*16)*1024 + (w*16)];
    abuf[i] = 0.f;
  }
  if (tid < 128) idt[tid] = expf(-(float)tid * (9.210340371976184f/128.f));
  __syncthreads();
  if (tid < 8){
    float s = 0.f;
    for (int i = 0; i < NHW; i++) s += dmask[tid*NHW + i];
    msum[tid] = s;
  }
  for (int p = tid; p < NB*NW; p += 256){
    int b = p >> 6, w = p & 63;
    float tot = 0.f;
    for (int h = 0; h < NH; h++) tot += dmask[b*NHW + h*64 + w];
    float inv = 6.283185307179586f/(tot + 1e-6f);
    float run = 0.f;
    for (int h = 0; h < NH; h++){ run += dmask[b*NHW + h*64 + w]; ys[b*NHW + h*64 + w] = run*inv; }
  }
  for (int p = tid; p < NB*NH; p += 256){
    int b = p >> 4, h = p & 15;
    float tot = 0.f;
    for (int w = 0; w < NW; w++) tot += dmask[b*NHW + h*64 + w];
    float inv = 6.283185307179586f/(tot + 1e-6f);
    float run = 0.f;
    for (int w = 0; w < NW; w++){ run += dmask[b*NHW + h*64 + w]; xs[b*NHW + h*64 + w] = run*inv; }
  }
}

// ---------------- P1: masked average
__global__ void k_avg(const float* __restrict__ cnn, const float* __restrict__ dmask,
                      const float* __restrict__ msum, float* __restrict__ avg)
{
  int gid = blockIdx.x*blockDim.x + threadIdx.x;
  int gw = gid >> 6, lane = gid & 63;
  int nw = (gridDim.x*blockDim.x) >> 6;
  for (int ow = gw; ow < NB*NC; ow += nw){
    int b = ow / NC;
    const float* base = cnn + (size_t)ow * NHW;
    const float* dm = dmask + b*NHW;
    float s = 0.f;
    for (int i = lane; i < NHW; i += 64) s += base[i]*dm[i];
    s = wred_sum(s);
    if (lane == 0) avg[ow] = s / msum[b];
  }
}

// ---------------- P2: hidden(-1) + counting_ctx
__global__ void k_init(const float* __restrict__ avg, const float* __restrict__ iW, const float* __restrict__ ib,
                       const float* __restrict__ cp, const float* __restrict__ cW, const float* __restrict__ cb,
                       float* __restrict__ hm1, float* __restrict__ cctx)
{
  int gid = blockIdx.x*blockDim.x + threadIdx.x;
  int gw = gid >> 6, lane = gid & 63;
  int nw = (gridDim.x*blockDim.x) >> 6;
  for (int ow = gw; ow < 2*NB*NHID; ow += nw){
    if (ow < NB*NHID){
      int b = ow >> 8, j = ow & 255;
      float s = 0.f;
      for (int k = lane; k < NC; k += 64) s += avg[b*NC + k]*iW[j*NC + k];
      s = wred_sum(s);
      if (lane == 0) hm1[ow] = tanhf(s + ib[j]);
    } else {
      int o = ow - NB*NHID; int b = o >> 8, j = o & 255;
      float s = 0.f;
      for (int k = lane; k < NV; k += 64) s += cp[b*NV + k]*cW[j*NV + k];
      s = wred_sum(s);
      if (lane == 0) cctx[o] = s + cb[j];
    }
  }
}

// ---------------- P3: trans GEMM (128x64 tile, 8x4/thread) + bias + sine pos-emb
// split into 4 launches over n (nb param) so loop kernels surface in rocprof top-5
__global__ __launch_bounds__(256) void k_trans(const float* __restrict__ cnn, const float* __restrict__ ew,
     const float* __restrict__ eb, const float* __restrict__ ys, const float* __restrict__ xs,
     const float* __restrict__ idt, float* __restrict__ trans, int nb)
{
  const int m0 = blockIdx.x << 7;
  const int n0 = (nb + blockIdx.y) << 6;
  const int b  = m0 >> 10;
  const int hw0 = m0 & 1023;
  __shared__ float As[16][132];
  __shared__ float Bs[16][68];
  const int tid = threadIdx.x;
  const int tx = tid & 15, ty = tid >> 4;
  float acc[8][4];
  #pragma unroll
  for (int i=0;i<8;i++)
    #pragma unroll
    for (int j=0;j<4;j++) acc[i][j]=0.f;
  for (int c0 = 0; c0 < NC; c0 += 16){
    #pragma unroll
    for (int u = 0; u < 8; u++){
      int idx = tid + (u<<8);
      int cc = idx >> 7, mm = idx & 127;
      int c = c0 + cc;
      As[cc][mm] = (c < NC) ? cnn[((size_t)b*NC + c)*NHW + hw0 + mm] : 0.f;
    }
    #pragma unroll
    for (int u = 0; u < 4; u++){
      int idx = tid + (u<<8);
      int nn = idx >> 4, cc = idx & 15;
      int c = c0 + cc;
      Bs[cc][nn] = (c < NC) ? ew[(size_t)(n0 + nn)*NC + c] : 0.f;
    }
    __syncthreads();
    #pragma unroll
    for (int k = 0; k < 16; k++){
      float4 a0 = *(const float4*)&As[k][ty*8];
      float4 a1 = *(const float4*)&As[k][ty*8+4];
      float4 bb = *(const float4*)&Bs[k][tx*4];
      float a[8] = {a0.x,a0.y,a0.z,a0.w,a1.x,a1.y,a1.z,a1.w};
      #pragma unroll
      for (int i=0;i<8;i++){
        acc[i][0] += a[i]*bb.x; acc[i][1] += a[i]*bb.y;
        acc[i][2] += a[i]*bb.z; acc[i][3] += a[i]*bb.w;
      }
    }
    __syncthreads();
  }
  const int dbase = n0 + tx*4;
  float ebv[4], idtv[4]; int codd[4];
  #pragma unroll
  for (int j = 0; j < 4; j++){
    int d = dbase + j;
    ebv[j] = eb[d];
    idtv[j] = (d < 256) ? idt[d>>1] : idt[(d-256)>>1];
    codd[j] = d & 1;
  }
  const int usex = dbase >= 256;
  #pragma unroll
  for (int i = 0; i < 8; i++){
    int hw = hw0 + ty*8 + i;
    float base = usex ? xs[(b<<10) + hw] : ys[(b<<10) + hw];
    float o[4];
    #pragma unroll
    for (int j = 0; j < 4; j++){
      float arg = base*idtv[j];
      float pe = codd[j] ? cosf(arg) : sinf(arg);
      o[j] = acc[i][j] + ebv[j] + pe;
    }
    *(float4*)(trans + ((size_t)(b<<10) + hw)*NAD + dbase) = make_float4(o[0],o[1],o[2],o[3]);
  }
}

// ---------------- P4: gi + embw for all steps
__global__ void k_pre(const int* __restrict__ labels, const float* __restrict__ emb,
    const float* __restrict__ wih, const float* __restrict__ bih,
    const float* __restrict__ ewW, const float* __restrict__ ewb,
    float* __restrict__ gi, float* __restrict__ embw)
{
  int gid = blockIdx.x*blockDim.x + threadIdx.x;
  int gw = gid >> 6, lane = gid & 63;
  int nw = (gridDim.x*blockDim.x) >> 6;
  const int NGI = NT*NB*768;
  const int NEW_ = NT*NB*256;
  for (int ow = gw; ow < NGI + NEW_; ow += nw){
    if (ow < NGI){
      int i = ow % 768; int tb = ow / 768; int b = tb & 7, t = tb >> 3;
      int word = (t == 0) ? 1 : labels[b*NT + t - 1];
      const float* er = emb + (size_t)word*256;
      float s = 0.f;
      for (int k = lane; k < 256; k += 64) s += er[k]*wih[(size_t)i*256 + k];
      s = wred_sum(s);
      if (lane == 0) gi[ow] = s + bih[i];
    } else {
      int o = ow - NGI; int j = o & 255; int tb = o >> 8; int b = tb & 7, t = tb >> 3;
      int word = (t == 0) ? 1 : labels[b*NT + t - 1];
      const float* er = emb + (size_t)word*256;
      float s = 0.f;
      for (int k = lane; k < 256; k += 64) s += er[k]*ewW[(size_t)j*256 + k];
      s = wred_sum(s);
      if (lane == 0) embw[o] = s + ewb[j];
    }
  }
}

// ---------------- P5: Mt[tap][d]
__global__ void k_mt(const float* __restrict__ aw, const float* __restrict__ acw, float* __restrict__ Mt)
{
  __shared__ float col[512];
  int t = blockIdx.x; int tid = threadIdx.x;
  for (int c = tid; c < 512; c += 256) col[c] = acw[(size_t)c*121 + t];
  __syncthreads();
  for (int d = tid; d < 512; d += 256){
    float s = 0.f;
    const float4* r4 = (const float4*)(aw + (size_t)d*512);
    for (int k = 0; k < 128; k++){
      float4 w = r4[k];
      s += col[k*4+0]*w.x + col[k*4+1]*w.y + col[k*4+2]*w.z + col[k*4+3]*w.w;
    }
    Mt[t*512 + d] = s;
  }
}

// ---------------- P6: SO = oW@sW; CB
__global__ __launch_bounds__(256) void k_so(const float* __restrict__ sW, const float* __restrict__ oW,
    const float* __restrict__ sb, const float* __restrict__ cxb, const float* __restrict__ cctx,
    const float* __restrict__ ob, float* __restrict__ SO, float* __restrict__ CB)
{
  const int v = blockIdx.x; const int tid = threadIdx.x;
  float acc = 0.f;
  for (int j = 0; j < 256; j++) acc += sW[(size_t)j*256 + tid] * oW[(size_t)v*256 + j];
  SO[(size_t)v*256 + tid] = acc;
  if (tid < 8){
    float s = ob[v];
    for (int j = 0; j < 256; j++) s += (sb[j] + cxb[j] + cctx[tid*256 + j]) * oW[(size_t)v*256 + j];
    CB[tid*NV + v] = s;
  }
}

// ---------------- P7: embwO
__global__ __launch_bounds__(512) void k_embwO(const float* __restrict__ embw, const float* __restrict__ oW,
                                               float* __restrict__ embwO)
{
  const int v = blockIdx.x; const int tid = threadIdx.x;
  const int lane = tid & 63, wid = tid >> 6;
  __shared__ float ows[256];
  if (tid < 256) ows[tid] = oW[(size_t)v*256 + tid];
  __syncthreads();
  for (int tb = wid; tb < NT*NB; tb += 8){
    float acc = 0.f;
    #pragma unroll
    for (int u = 0; u < 4; u++){ int j = lane + (u<<6); acc += embw[(size_t)tb*256 + j]*ows[j]; }
    acc = wred_sum(acc);
    if (lane == 0) embwO[tb*NV + v] = acc;
  }
}

// ---------------- P8: CO[c][v]
__global__ __launch_bounds__(256) void k_co(const float* __restrict__ cxW, const float* __restrict__ oW,
                                            float* __restrict__ CO)
{
  const int c = blockIdx.x*256 + threadIdx.x;
  const int v = blockIdx.y;
  if (c >= NC) return;
  float acc = 0.f;
  for (int j = 0; j < 256; j++) acc += cxW[(size_t)j*NC + c] * oW[(size_t)v*256 + j];
  CO[(size_t)c*128 + v] = acc;
  if (v == 0){
    for (int vv = NV; vv < 128; vv++) CO[(size_t)c*128 + vv] = 0.f;
  }
}

// ---------------- P9: PO GEMM (64x64 tile, 4x4/thread)
__global__ __launch_bounds__(256) void k_gemm_PO(const float* __restrict__ cnn, const float* __restrict__ CO,
                                                 float* __restrict__ PO)
{
  const int m0 = blockIdx.x << 6;
  const int n0 = blockIdx.y << 6;
  const int b  = blockIdx.z;
  __shared__ float As[32][64];
  __shared__ float Bs[32][65];
  const int tid = threadIdx.x;
  const int tx = tid & 15, ty = tid >> 4;
  float acc[4][4];
  #pragma unroll
  for (int i=0;i<4;i++)
    #pragma unroll
    for (int j=0;j<4;j++) acc[i][j]=0.f;
  for (int c0 = 0; c0 < NC; c0 += 32){
    int kc = NC - c0; if (kc > 32) kc = 32;
    for (int idx = tid; idx < 32*64; idx += 256){
      int cc = idx >> 6, mm = idx & 63;
      As[cc][mm] = (cc < kc) ? cnn[((size_t)b*NC + c0 + cc)*NHW + m0 + mm] : 0.f;
    }
    for (int idx = tid; idx < 32*64; idx += 256){
      int cc = idx >> 6, nn = idx & 63;
      Bs[cc][nn] = (cc < kc) ? CO[(size_t)(c0 + cc)*128 + n0 + nn] : 0.f;
    }
    __syncthreads();
    #pragma unroll
    for (int k = 0; k < 32; k++){
      float a0 = As[k][tx*4+0], a1 = As[k][tx*4+1], a2 = As[k][tx*4+2], a3 = As[k][tx*4+3];
      float b0 = Bs[k][ty*4+0], b1 = Bs[k][ty*4+1], b2 = Bs[k][ty*4+2], b3 = Bs[k][ty*4+3];
      acc[0][0]+=a0*b0; acc[0][1]+=a0*b1; acc[0][2]+=a0*b2; acc[0][3]+=a0*b3;
      acc[1][0]+=a1*b0; acc[1][1]+=a1*b1; acc[1][2]+=a1*b2; acc[1][3]+=a1*b3;
      acc[2][0]+=a2*b0; acc[2][1]+=a2*b1; acc[2][2]+=a2*b2; acc[2][3]+=a2*b3;
      acc[3][0]+=a3*b0; acc[3][1]+=a3*b1; acc[3][2]+=a3*b2; acc[3][3]+=a3*b3;
    }
    __syncthreads();
  }
  #pragma unroll
  for (int j = 0; j < 4; j++){
    int v = n0 + ty*4 + j;
    float* dst = PO + (((size_t)b*128 + v)<<10) + m0 + tx*4;
    *(float4*)dst = make_float4(acc[0][j],acc[1][j],acc[2][j],acc[3][j]);
  }
}

// ---------------- gru slice helper — prologue only (fp32 weights)
__device__ __forceinline__ void gru_slice(const float* __restrict__ hs, const float* __restrict__ whh,
    const float* __restrict__ bhh, const float* __restrict__ gg, float* __restrict__ hdst,
    int r, int wid, int lane)
{
  #pragma unroll 1
  for (int jj = 0; jj < 8; jj++){
    int j = (r<<6) + (wid<<3) + jj;
    float sr = 0.f, sz = 0.f, sn = 0.f;
    #pragma unroll
    for (int u = 0; u < 4; u++){
      int k = lane + (u<<6);
      float hv = hs[k];
      sr += hv * whh[(size_t)j*256 + k];
      sz += hv * whh[(size_t)(j+256)*256 + k];
      sn += hv * whh[(size_t)(j+512)*256 + k];
    }
    sr = wred_sum(sr); sz = wred_sum(sz); sn = wred_sum(sn);
    if (lane == 0){
      float rr = 1.f/(1.f + expf(-(gg[j] + sr + bhh[j])));
      float zz = 1.f/(1.f + expf(-(gg[j+256] + sz + bhh[j+256])));
      float nn = tanhf(gg[j+512] + rr*(sn + bhh[j+512]));
      hdst[j] = (1.f - zz)*nn + zz*hs[j];
    }
  }
}

// ---------------- P10: initial GRU: hm1 -> h(0) (hbuf3 slot 0)
__global__ __launch_bounds__(512) void k_gq0(const float* __restrict__ hm1, const float* __restrict__ whh,
    const float* __restrict__ bhh, const float* __restrict__ gi, float* __restrict__ hbuf3)
{
  const int r = blockIdx.x, b = blockIdx.y;
  const int tid = threadIdx.x, lane = tid & 63, wid = tid >> 6;
  __shared__ float hs[256];
  if (tid < 256) hs[tid] = hm1[(b<<8) + tid];
  __syncthreads();
  gru_slice(hs, whh, bhh, gi + (size_t)b*768, hbuf3 + (b<<8), r, wid, lane);
}

// ---------------- P11: query(0) into qbuf slot 0 (fp32 ahW)
__global__ __launch_bounds__(512) void k_query0(const float* __restrict__ hbuf3, const float* __restrict__ ahW,
    const float* __restrict__ ahb, float* __restrict__ qbuf)
{
  const int b = blockIdx.x >> 3, dc = blockIdx.x & 7;
  const int tid = threadIdx.x, lane = tid & 63, wid = tid >> 6;
  __shared__ float hs[256];
  if (tid < 256) hs[tid] = hbuf3[(b<<8) + tid];
  __syncthreads();
  #pragma unroll 1
  for (int i = 0; i < 8; i++){
    int d = (dc<<6) + (wid<<3) + i;
    float acc = 0.f;
    #pragma unroll
    for (int u = 0; u < 4; u++){ int k = lane + (u<<6); acc += hs[k]*ahW[(size_t)d*256 + k]; }
    acc = wred_sum(acc);
    if (lane == 0) qbuf[(b<<9) + d] = acc + ahb[d];
  }
}

// ---------------- P12: bf16-packed weight transposes for the in-loop gru/query
// whhTb[(g*128+kp)*256 + j] = {w(2kp), w(2kp+1)} of whh[(g*256+j)][k]
// ahWTb[kp*512 + d]         = {ahW[d][2kp], ahW[d][2kp+1]}
__global__ void k_tr(const float* __restrict__ whh, const float* __restrict__ ahW,
                     __hip_bfloat162* __restrict__ whhTb, __hip_bfloat162* __restrict__ ahWTb)
{
  int i = blockIdx.x*256 + threadIdx.x;
  int stride = gridDim.x*256;
  for (int x = i; x < 3*128*256; x += stride){
    int j = x & 255, kp = (x >> 8) & 127, g = x >> 15;
    float lo = whh[(size_t)((g<<8)+j)*256 + (kp<<1)];
    float hi = whh[(size_t)((g<<8)+j)*256 + (kp<<1) + 1];
    __hip_bfloat162 h2; h2.x = __float2bfloat16(lo); h2.y = __float2bfloat16(hi);
    whhTb[x] = h2;
  }
  for (int x = i; x < 128*512; x += stride){
    int d = x & 511, kp = x >> 9;
    float lo = ahW[(size_t)d*256 + (kp<<1)];
    float hi = ahW[(size_t)d*256 + (kp<<1) + 1];
    __hip_bfloat162 h2; h2.x = __float2bfloat16(lo); h2.y = __float2bfloat16(hi);
    ahWTb[x] = h2;
  }
}

// ================= per-step kernel (one launch per t, t = 0..NT) =================
__global__ __launch_bounds__(512) void k_step(
  const float* __restrict__ dmask, const float* __restrict__ Mt,
  const float* __restrict__ trans, float* __restrict__ qbuf,
  const float* __restrict__ acvW, const float* __restrict__ acvb,
  const float* __restrict__ PO, const float* __restrict__ SO,
  const float* __restrict__ CB, const float* __restrict__ embwO,
  const float* __restrict__ gi, const __hip_bfloat162* __restrict__ whhTb,
  const float* __restrict__ bhh, const __hip_bfloat162* __restrict__ ahWTb,
  const float* __restrict__ ahb, float* __restrict__ hbuf3,
  float* __restrict__ abuf, float* __restrict__ ebuf,
  float* __restrict__ out, int t)
{
  const int gid = blockIdx.x, tid = threadIdx.x;
  const int lane = tid & 63, wv = tid >> 6;
  __shared__ float eo8[8][512];
  __shared__ float al[1024];
  __shared__ float as4[11][44];
  __shared__ float hs[256], hn[256];
  __shared__ float red[18];

  const float* eprev = ebuf + (((t+1)&1)<<13);
  float*       ecurb = ebuf + ((t&1)<<13);
  const float* aprev = abuf + (((t+1)&1)<<13);
  float*       acur  = abuf + ((t&1)<<13);

  if (gid < 256){
    const int b = gid >> 5, seg = gid & 31, h = seg >> 1, w0 = (seg & 1) << 5;
    if (t > 0){
      // ---- softmax(e(t-1)) -> al
      float e0 = eprev[(b<<10)+tid], e1 = eprev[(b<<10)+512+tid];
      float dm0 = dmask[(b<<10)+tid], dm1 = dmask[(b<<10)+512+tid];
      float m = wred_max(fmaxf(e0, e1));
      if (lane == 0) red[wv] = m;
      __syncthreads();
      if (tid == 0){
        float g = red[0];
        #pragma unroll
        for (int k = 1; k < 8; k++) g = fmaxf(g, red[k]);
        red[16] = g;
      }
      __syncthreads();
      float g = red[16];
      float x0 = __expf(e0 - g)*dm0, x1 = __expf(e1 - g)*dm1;
      float s = wred_sum(x0 + x1);
      if (lane == 0) red[wv] = s;
      __syncthreads();
      if (tid == 0){
        float ss = 0.f;
        #pragma unroll
        for (int k = 0; k < 8; k++) ss += red[k];
        red[17] = ss;
      }
      __syncthreads();
      float inv = 1.f/(red[17] + 1e-10f);
      al[tid] = x0*inv; al[512+tid] = x1*inv;
      __syncthreads();
      // ---- prob(t-1): waves 0..3, v = seg + 32*wv
      if (wv < 4){
        int v = seg + (wv<<5);
        if (v < NV){
          const float* POr = PO + (((size_t)b*128 + v)<<10);
          const float* hr = hbuf3 + ((t-1)%3)*2048 + (b<<8);
          const float* SOr = SO + (size_t)v*256;
          float a2 = 0.f;
          #pragma unroll
          for (int u = 0; u < 16; u++){ int p = lane + (u<<6); a2 += al[p]*POr[p]; }
          #pragma unroll
          for (int u = 0; u < 4; u++){ int k = lane + (u<<6); a2 += hr[k]*SOr[k]; }
          a2 = wred_sum(a2);
          if (lane == 0)
            out[((size_t)b*NT + (t-1))*NV + v] = a2 + CB[b*NV + v] + embwO[(((t-1)<<3)+b)*NV + v];
        }
      }
    }
    if (t < NT){
      // ---- halo: as4 = A(t-1) + alpha(t-1)  (44-wide rows, cols 42..43 zeroed)
      for (int idx = tid; idx < 11*44; idx += 512){
        int r = idx/44, c = idx - r*44;
        float v = 0.f;
        if (t > 0 && c < 42){
          int hi2 = h + r - 5, wi = w0 + c - 5;
          if ((unsigned)hi2 < 16u && (unsigned)wi < 64u){
            int p = (hi2<<6) + wi;
            v = aprev[(b<<10)+p] + al[p];
          }
        }
        as4[r][c] = v;
      }
      __syncthreads();
      // ---- stencil: thread owns d=tid; static hi-bounds row skip; float4 row loads
      float accw[32];
      #pragma unroll
      for (int w = 0; w < 32; w++) accw[w] = 0.f;
      if (t > 0){
        #pragma unroll 1
        for (int ki = 0; ki < 11; ki++){
          int hi2 = h + ki - 5;
          if ((unsigned)hi2 >= 16u) continue;
          float row[44];
          #pragma unroll
          for (int i4 = 0; i4 < 11; i4++)
            *(float4*)&row[i4*4] = *(const float4*)&as4[ki][i4*4];
          const float* mrow = Mt + ki*11*512 + tid;
          #pragma unroll
          for (int kj = 0; kj < 11; kj++){
            float m = mrow[kj*512];
            #pragma unroll
            for (int w = 0; w < 32; w++) accw[w] += row[kj + w]*m;
          }
        }
      }
      // ---- tail: tanh -> chunked eo8 transpose -> wave-parallel reduce
      const float wav = acvW[tid];
      const float acb0 = acvb[0];
      float q = qbuf[((t&1)<<12) + (b<<9) + tid];
      const float* tbase = trans + (((size_t)(b<<10) + (h<<6) + w0))*NAD + tid;
      float* ecur = ecurb + (b<<10) + (h<<6) + w0;
      #pragma unroll 1
      for (int chunk = 0; chunk < 4; chunk++){
        __syncthreads();
        #pragma unroll
        for (int k = 0; k < 8; k++){
          int w = (chunk<<3) + k;
          eo8[k][tid] = wav * ftanh(q + tbase[(size_t)w*NAD] + accw[w]);
        }
        __syncthreads();
        {
          float sum = 0.f;
          #pragma unroll
          for (int u = 0; u < 8; u++) sum += eo8[wv][lane + (u<<6)];
          sum = wred_sum(sum);
          if (lane == 0) ecur[(chunk<<3) + wv] = sum + acb0;
        }
      }
    }
  } else {
    // ---- aux block for batch b: softmax + A-write; gru+query(t+1) with bf16 weights
    const int b = gid - 256;
    if (t > 0){
      float e0 = eprev[(b<<10)+tid], e1 = eprev[(b<<10)+512+tid];
      float dm0 = dmask[(b<<10)+tid], dm1 = dmask[(b<<10)+512+tid];
      float m = wred_max(fmaxf(e0, e1));
      if (lane == 0) red[wv] = m;
      __syncthreads();
      if (tid == 0){
        float g = red[0];
        #pragma unroll
        for (int k = 1; k < 8; k++) g = fmaxf(g, red[k]);
        red[16] = g;
      }
      __syncthreads();
      float g = red[16];
      float x0 = __expf(e0 - g)*dm0, x1 = __expf(e1 - g)*dm1;
      float s = wred_sum(x0 + x1);
      if (lane == 0) red[wv] = s;
      __syncthreads();
      if (tid == 0){
        float ss = 0.f;
        #pragma unroll
        for (int k = 0; k < 8; k++) ss += red[k];
        red[17] = ss;
      }
      __syncthreads();
      float inv = 1.f/(red[17] + 1e-10f);
      if (t < NT){
        acur[(b<<10)+tid]     = aprev[(b<<10)+tid]     + x0*inv;
        acur[(b<<10)+512+tid] = aprev[(b<<10)+512+tid] + x1*inv;
      }
    }
    if (t < NT-1){
      if (tid < 256) hs[tid] = hbuf3[(t%3)*2048 + (b<<8) + tid];
      __syncthreads();
      if (tid < 256){
        const int j = tid;
        float sr = 0.f, sz = 0.f, sn = 0.f;
        #pragma unroll 4
        for (int kp = 0; kp < 128; kp++){
          float h0 = hs[kp<<1], h1 = hs[(kp<<1)+1];
          __hip_bfloat162 w0 = whhTb[(kp<<8) + j];
          __hip_bfloat162 w1 = whhTb[32768 + (kp<<8) + j];
          __hip_bfloat162 w2 = whhTb[65536 + (kp<<8) + j];
          sr += h0*__bfloat162float(w0.x) + h1*__bfloat162float(w0.y);
          sz += h0*__bfloat162float(w1.x) + h1*__bfloat162float(w1.y);
          sn += h0*__bfloat162float(w2.x) + h1*__bfloat162float(w2.y);
        }
        const float* gg = gi + (size_t)(((t+1)<<3) + b)*768;
        float r = fsig(gg[j] + sr + bhh[j]);
        float z = fsig(gg[j+256] + sz + bhh[j+256]);
        float n = ftanh(gg[j+512] + r*(sn + bhh[j+512]));
        float hv2 = (1.f - z)*n + z*hs[j];
        hn[j] = hv2;
        hbuf3[((t+1)%3)*2048 + (b<<8) + j] = hv2;
      }
      __syncthreads();
      {
        const int d = tid;
        float s2 = 0.f;
        #pragma unroll 4
        for (int kp = 0; kp < 128; kp++){
          __hip_bfloat162 w = ahWTb[(kp<<9) + d];
          s2 += hn[kp<<1]*__bfloat162float(w.x) + hn[(kp<<1)+1]*__bfloat162float(w.y);
        }
        qbuf[(((t+1)&1)<<12) + (b<<9) + d] = s2 + ahb[d];
      }
    }
  }
}

extern "C" void kernel_launch(void* const* d_in, const int* in_sizes, int n_in,
                              void* d_out, int out_size, void* d_ws, size_t ws_size,
                              hipStream_t stream)
{
  const float* cnn  = (const float*)d_in[0];
  const float* cp   = (const float*)d_in[1];
  const float* im   = (const float*)d_in[2];
  const float* iW   = (const float*)d_in[3];
  const float* ib   = (const float*)d_in[4];
  const float* emb  = (const float*)d_in[5];
  const float* wih  = (const float*)d_in[6];
  const float* whh  = (const float*)d_in[7];
  const float* bih  = (const float*)d_in[8];
  const float* bhh  = (const float*)d_in[9];
  const float* ahW  = (const float*)d_in[10];
  const float* ahb  = (const float*)d_in[11];
  const float* acw  = (const float*)d_in[12];
  const float* awW  = (const float*)d_in[13];
  const float* acvW = (const float*)d_in[14];
  const float* acvb = (const float*)d_in[15];
  const float* ecw  = (const float*)d_in[16];
  const float* ecb  = (const float*)d_in[17];
  const float* sW   = (const float*)d_in[18];
  const float* sb   = (const float*)d_in[19];
  const float* ewW  = (const float*)d_in[20];
  const float* ewb  = (const float*)d_in[21];
  const float* cxW  = (const float*)d_in[22];
  const float* cxb  = (const float*)d_in[23];
  const float* cW   = (const float*)d_in[24];
  const float* cb   = (const float*)d_in[25];
  const float* oW   = (const float*)d_in[26];
  const float* ob   = (const float*)d_in[27];
  const int*   lab  = (const int*)d_in[28];
  float* out = (float*)d_out;
  float* ws = (float*)d_ws;

  float* dmask  = ws + 0;        // 8192
  float* ys     = ws + 8192;     // 8192
  float* xs     = ws + 16384;    // 8192
  float* idt    = ws + 24576;    // 128
  float* msum   = ws + 24704;    // 16
  float* avg    = ws + 24720;    // 5472
  float* cctx   = ws + 30192;    // 2048
  float* hm1    = ws + 32240;    // 2048
  float* hbuf3  = ws + 34288;    // 6144 (3 x 8 x 256)
  float* qbuf   = ws + 40432;    // 8192 (2 x 8 x 512)
  float* abuf   = ws + 48624;    // 16384 (2 x 8 x 1024)
  float* ebuf   = ws + 65008;    // 16384
  float* gi     = ws + 81392;    // 221184
  float* embw   = ws + 302576;   // 73728
  float* Mt     = ws + 376304;   // 61952
  float* SO     = ws + 438256;   // 28416
  float* CB     = ws + 466672;   // 896
  float* embwO  = ws + 467568;   // 32000
  float* CO     = ws + 499568;   // 87552
  __hip_bfloat162* whhTb = (__hip_bfloat162*)(ws + 587120);  // 98304 words
  __hip_bfloat162* ahWTb = (__hip_bfloat162*)(ws + 685424);  // 65536 words
  float* trans  = ws + 750960;   // 4194304
  float* PO     = ws + 4945264;  // 4194304   (total ~36.6 MB)

  k_p0<<<1, 256, 0, stream>>>(im, dmask, msum, ys, xs, idt, abuf);
  k_avg<<<456, 256, 0, stream>>>(cnn, dmask, msum, avg);
  k_init<<<256, 256, 0, stream>>>(avg, iW, ib, cp, cW, cb, hm1, cctx);
  k_pre<<<1024, 256, 0, stream>>>(lab, emb, wih, bih, ewW, ewb, gi, embw);
  for (int nb = 0; nb < 8; nb += 2)
    k_trans<<<dim3(64, 2), 256, 0, stream>>>(cnn, ecw, ecb, ys, xs, idt, trans, nb);
  k_mt<<<121, 256, 0, stream>>>(awW, acw, Mt);
  k_so<<<NV, 256, 0, stream>>>(sW, oW, sb, cxb, cctx, ob, SO, CB);
  k_embwO<<<NV, 512, 0, stream>>>(embw, oW, embwO);
  k_co<<<dim3(3, NV), 256, 0, stream>>>(cxW, oW, CO);
  k_gemm_PO<<<dim3(16, 2, 8), 256, 0, stream>>>(cnn, CO, PO);
  k_tr<<<128, 256, 0, stream>>>(whh, ahW, whhTb, ahWTb);
  k_gq0<<<dim3(4, 8), 512, 0, stream>>>(hm1, whh, bhh, gi, hbuf3);
  k_query0<<<64, 512, 0, stream>>>(hbuf3, ahW, ahb, qbuf);

  for (int t = 0; t <= NT; t++){
    k_step<<<264, 512, 0, stream>>>(dmask, Mt, trans, qbuf, acvW, acvb, PO, SO, CB, embwO,
                                    gi, whhTb, bhh, ahWTb, ahb, hbuf3, abuf, ebuf, out, t);
  }
}

// Round 10
// 1832.001 us; speedup vs baseline: 3.9230x; 1.1077x over previous
//
#include <hip/hip_runtime.h>
#include <hip/hip_bf16.h>
#include <math.h>

#define NB 8
#define NC 684
#define NH 16
#define NW 64
#define NHW 1024
#define NHID 256
#define NAD 512
#define NV 111
#define NT 36

__device__ __forceinline__ float wred_sum(float v){
  #pragma unroll
  for (int o = 32; o > 0; o >>= 1) v += __shfl_xor(v, o, 64);
  return v;
}
__device__ __forceinline__ float wred_max(float v){
  #pragma unroll
  for (int o = 32; o > 0; o >>= 1) v = fmaxf(v, __shfl_xor(v, o, 64));
  return v;
}
__device__ __forceinline__ float fsig(float x){ return 1.f/(1.f + __expf(-x)); }
__device__ __forceinline__ float ftanh(float x){ float e = __expf(2.f*x); return 1.f - 2.f/(e + 1.f); }

// ---------------- P0: dmask, msum, ys/xs, idt, zero abuf[0]
__global__ void k_p0(const float* __restrict__ im, float* __restrict__ dmask,
                     float* __restrict__ msum, float* __restrict__ ys, float* __restrict__ xs,
                     float* __restrict__ idt, float* __restrict__ abuf)
{
  const int tid = threadIdx.x; // 256 threads, 1 block
  for (int i = tid; i < NB*NHW; i += 256){
    int b = i >> 10, hw = i & 1023; int h = hw >> 6, w = hw & 63;
    dmask[i] = im[b*(256*1024) + (h*16)*1024 + (w*16)];
    abuf[i] = 0.f;
  }
  if (tid < 128) idt[tid] = expf(-(float)tid * (9.210340371976184f/128.f));
  __syncthreads();
  if (tid < 8){
    float s = 0.f;
    for (int i = 0; i < NHW; i++) s += dmask[tid*NHW + i];
    msum[tid] = s;
  }
  for (int p = tid; p < NB*NW; p += 256){
    int b = p >> 6, w = p & 63;
    float tot = 0.f;
    for (int h = 0; h < NH; h++) tot += dmask[b*NHW + h*64 + w];
    float inv = 6.283185307179586f/(tot + 1e-6f);
    float run = 0.f;
    for (int h = 0; h < NH; h++){ run += dmask[b*NHW + h*64 + w]; ys[b*NHW + h*64 + w] = run*inv; }
  }
  for (int p = tid; p < NB*NH; p += 256){
    int b = p >> 4, h = p & 15;
    float tot = 0.f;
    for (int w = 0; w < NW; w++) tot += dmask[b*NHW + h*64 + w];
    float inv = 6.283185307179586f/(tot + 1e-6f);
    float run = 0.f;
    for (int w = 0; w < NW; w++){ run += dmask[b*NHW + h*64 + w]; xs[b*NHW + h*64 + w] = run*inv; }
  }
}

// ---------------- P1: masked average
__global__ void k_avg(const float* __restrict__ cnn, const float* __restrict__ dmask,
                      const float* __restrict__ msum, float* __restrict__ avg)
{
  int gid = blockIdx.x*blockDim.x + threadIdx.x;
  int gw = gid >> 6, lane = gid & 63;
  int nw = (gridDim.x*blockDim.x) >> 6;
  for (int ow = gw; ow < NB*NC; ow += nw){
    int b = ow / NC;
    const float* base = cnn + (size_t)ow * NHW;
    const float* dm = dmask + b*NHW;
    float s = 0.f;
    for (int i = lane; i < NHW; i += 64) s += base[i]*dm[i];
    s = wred_sum(s);
    if (lane == 0) avg[ow] = s / msum[b];
  }
}

// ---------------- P2: hidden(-1) + counting_ctx
__global__ void k_init(const float* __restrict__ avg, const float* __restrict__ iW, const float* __restrict__ ib,
                       const float* __restrict__ cp, const float* __restrict__ cW, const float* __restrict__ cb,
                       float* __restrict__ hm1, float* __restrict__ cctx)
{
  int gid = blockIdx.x*blockDim.x + threadIdx.x;
  int gw = gid >> 6, lane = gid & 63;
  int nw = (gridDim.x*blockDim.x) >> 6;
  for (int ow = gw; ow < 2*NB*NHID; ow += nw){
    if (ow < NB*NHID){
      int b = ow >> 8, j = ow & 255;
      float s = 0.f;
      for (int k = lane; k < NC; k += 64) s += avg[b*NC + k]*iW[j*NC + k];
      s = wred_sum(s);
      if (lane == 0) hm1[ow] = tanhf(s + ib[j]);
    } else {
      int o = ow - NB*NHID; int b = o >> 8, j = o & 255;
      float s = 0.f;
      for (int k = lane; k < NV; k += 64) s += cp[b*NV + k]*cW[j*NV + k];
      s = wred_sum(s);
      if (lane == 0) cctx[o] = s + cb[j];
    }
  }
}

// ---------------- P3: trans GEMM (128x64 tile, 8x4/thread) + bias + sine pos-emb (single launch)
__global__ __launch_bounds__(256) void k_trans(const float* __restrict__ cnn, const float* __restrict__ ew,
     const float* __restrict__ eb, const float* __restrict__ ys, const float* __restrict__ xs,
     const float* __restrict__ idt, float* __restrict__ trans)
{
  const int m0 = blockIdx.x << 7;
  const int n0 = blockIdx.y << 6;
  const int b  = m0 >> 10;
  const int hw0 = m0 & 1023;
  __shared__ float As[16][132];
  __shared__ float Bs[16][68];
  const int tid = threadIdx.x;
  const int tx = tid & 15, ty = tid >> 4;
  float acc[8][4];
  #pragma unroll
  for (int i=0;i<8;i++)
    #pragma unroll
    for (int j=0;j<4;j++) acc[i][j]=0.f;
  for (int c0 = 0; c0 < NC; c0 += 16){
    #pragma unroll
    for (int u = 0; u < 8; u++){
      int idx = tid + (u<<8);
      int cc = idx >> 7, mm = idx & 127;
      int c = c0 + cc;
      As[cc][mm] = (c < NC) ? cnn[((size_t)b*NC + c)*NHW + hw0 + mm] : 0.f;
    }
    #pragma unroll
    for (int u = 0; u < 4; u++){
      int idx = tid + (u<<8);
      int nn = idx >> 4, cc = idx & 15;
      int c = c0 + cc;
      Bs[cc][nn] = (c < NC) ? ew[(size_t)(n0 + nn)*NC + c] : 0.f;
    }
    __syncthreads();
    #pragma unroll
    for (int k = 0; k < 16; k++){
      float4 a0 = *(const float4*)&As[k][ty*8];
      float4 a1 = *(const float4*)&As[k][ty*8+4];
      float4 bb = *(const float4*)&Bs[k][tx*4];
      float a[8] = {a0.x,a0.y,a0.z,a0.w,a1.x,a1.y,a1.z,a1.w};
      #pragma unroll
      for (int i=0;i<8;i++){
        acc[i][0] += a[i]*bb.x; acc[i][1] += a[i]*bb.y;
        acc[i][2] += a[i]*bb.z; acc[i][3] += a[i]*bb.w;
      }
    }
    __syncthreads();
  }
  const int dbase = n0 + tx*4;
  float ebv[4], idtv[4]; int codd[4];
  #pragma unroll
  for (int j = 0; j < 4; j++){
    int d = dbase + j;
    ebv[j] = eb[d];
    idtv[j] = (d < 256) ? idt[d>>1] : idt[(d-256)>>1];
    codd[j] = d & 1;
  }
  const int usex = dbase >= 256;
  #pragma unroll
  for (int i = 0; i < 8; i++){
    int hw = hw0 + ty*8 + i;
    float base = usex ? xs[(b<<10) + hw] : ys[(b<<10) + hw];
    float o[4];
    #pragma unroll
    for (int j = 0; j < 4; j++){
      float arg = base*idtv[j];
      float pe = codd[j] ? cosf(arg) : sinf(arg);
      o[j] = acc[i][j] + ebv[j] + pe;
    }
    *(float4*)(trans + ((size_t)(b<<10) + hw)*NAD + dbase) = make_float4(o[0],o[1],o[2],o[3]);
  }
}

// ---------------- P4: gi + embw for all steps
__global__ void k_pre(const int* __restrict__ labels, const float* __restrict__ emb,
    const float* __restrict__ wih, const float* __restrict__ bih,
    const float* __restrict__ ewW, const float* __restrict__ ewb,
    float* __restrict__ gi, float* __restrict__ embw)
{
  int gid = blockIdx.x*blockDim.x + threadIdx.x;
  int gw = gid >> 6, lane = gid & 63;
  int nw = (gridDim.x*blockDim.x) >> 6;
  const int NGI = NT*NB*768;
  const int NEW_ = NT*NB*256;
  for (int ow = gw; ow < NGI + NEW_; ow += nw){
    if (ow < NGI){
      int i = ow % 768; int tb = ow / 768; int b = tb & 7, t = tb >> 3;
      int word = (t == 0) ? 1 : labels[b*NT + t - 1];
      const float* er = emb + (size_t)word*256;
      float s = 0.f;
      for (int k = lane; k < 256; k += 64) s += er[k]*wih[(size_t)i*256 + k];
      s = wred_sum(s);
      if (lane == 0) gi[ow] = s + bih[i];
    } else {
      int o = ow - NGI; int j = o & 255; int tb = o >> 8; int b = tb & 7, t = tb >> 3;
      int word = (t == 0) ? 1 : labels[b*NT + t - 1];
      const float* er = emb + (size_t)word*256;
      float s = 0.f;
      for (int k = lane; k < 256; k += 64) s += er[k]*ewW[(size_t)j*256 + k];
      s = wred_sum(s);
      if (lane == 0) embw[o] = s + ewb[j];
    }
  }
}

// ---------------- P5: Mt[tap][d]
__global__ void k_mt(const float* __restrict__ aw, const float* __restrict__ acw, float* __restrict__ Mt)
{
  __shared__ float col[512];
  int t = blockIdx.x; int tid = threadIdx.x;
  for (int c = tid; c < 512; c += 256) col[c] = acw[(size_t)c*121 + t];
  __syncthreads();
  for (int d = tid; d < 512; d += 256){
    float s = 0.f;
    const float4* r4 = (const float4*)(aw + (size_t)d*512);
    for (int k = 0; k < 128; k++){
      float4 w = r4[k];
      s += col[k*4+0]*w.x + col[k*4+1]*w.y + col[k*4+2]*w.z + col[k*4+3]*w.w;
    }
    Mt[t*512 + d] = s;
  }
}

// ---------------- P6: SO = oW@sW; CB
__global__ __launch_bounds__(256) void k_so(const float* __restrict__ sW, const float* __restrict__ oW,
    const float* __restrict__ sb, const float* __restrict__ cxb, const float* __restrict__ cctx,
    const float* __restrict__ ob, float* __restrict__ SO, float* __restrict__ CB)
{
  const int v = blockIdx.x; const int tid = threadIdx.x;
  float acc = 0.f;
  for (int j = 0; j < 256; j++) acc += sW[(size_t)j*256 + tid] * oW[(size_t)v*256 + j];
  SO[(size_t)v*256 + tid] = acc;
  if (tid < 8){
    float s = ob[v];
    for (int j = 0; j < 256; j++) s += (sb[j] + cxb[j] + cctx[tid*256 + j]) * oW[(size_t)v*256 + j];
    CB[tid*NV + v] = s;
  }
}

// ---------------- P7: embwO
__global__ __launch_bounds__(512) void k_embwO(const float* __restrict__ embw, const float* __restrict__ oW,
                                               float* __restrict__ embwO)
{
  const int v = blockIdx.x; const int tid = threadIdx.x;
  const int lane = tid & 63, wid = tid >> 6;
  __shared__ float ows[256];
  if (tid < 256) ows[tid] = oW[(size_t)v*256 + tid];
  __syncthreads();
  for (int tb = wid; tb < NT*NB; tb += 8){
    float acc = 0.f;
    #pragma unroll
    for (int u = 0; u < 4; u++){ int j = lane + (u<<6); acc += embw[(size_t)tb*256 + j]*ows[j]; }
    acc = wred_sum(acc);
    if (lane == 0) embwO[tb*NV + v] = acc;
  }
}

// ---------------- P8: CO[c][v]
__global__ __launch_bounds__(256) void k_co(const float* __restrict__ cxW, const float* __restrict__ oW,
                                            float* __restrict__ CO)
{
  const int c = blockIdx.x*256 + threadIdx.x;
  const int v = blockIdx.y;
  if (c >= NC) return;
  float acc = 0.f;
  for (int j = 0; j < 256; j++) acc += cxW[(size_t)j*NC + c] * oW[(size_t)v*256 + j];
  CO[(size_t)c*128 + v] = acc;
  if (v == 0){
    for (int vv = NV; vv < 128; vv++) CO[(size_t)c*128 + vv] = 0.f;
  }
}

// ---------------- P9: PO GEMM (64x64 tile, 4x4/thread)
__global__ __launch_bounds__(256) void k_gemm_PO(const float* __restrict__ cnn, const float* __restrict__ CO,
                                                 float* __restrict__ PO)
{
  const int m0 = blockIdx.x << 6;
  const int n0 = blockIdx.y << 6;
  const int b  = blockIdx.z;
  __shared__ float As[32][64];
  __shared__ float Bs[32][65];
  const int tid = threadIdx.x;
  const int tx = tid & 15, ty = tid >> 4;
  float acc[4][4];
  #pragma unroll
  for (int i=0;i<4;i++)
    #pragma unroll
    for (int j=0;j<4;j++) acc[i][j]=0.f;
  for (int c0 = 0; c0 < NC; c0 += 32){
    int kc = NC - c0; if (kc > 32) kc = 32;
    for (int idx = tid; idx < 32*64; idx += 256){
      int cc = idx >> 6, mm = idx & 63;
      As[cc][mm] = (cc < kc) ? cnn[((size_t)b*NC + c0 + cc)*NHW + m0 + mm] : 0.f;
    }
    for (int idx = tid; idx < 32*64; idx += 256){
      int cc = idx >> 6, nn = idx & 63;
      Bs[cc][nn] = (cc < kc) ? CO[(size_t)(c0 + cc)*128 + n0 + nn] : 0.f;
    }
    __syncthreads();
    #pragma unroll
    for (int k = 0; k < 32; k++){
      float a0 = As[k][tx*4+0], a1 = As[k][tx*4+1], a2 = As[k][tx*4+2], a3 = As[k][tx*4+3];
      float b0 = Bs[k][ty*4+0], b1 = Bs[k][ty*4+1], b2 = Bs[k][ty*4+2], b3 = Bs[k][ty*4+3];
      acc[0][0]+=a0*b0; acc[0][1]+=a0*b1; acc[0][2]+=a0*b2; acc[0][3]+=a0*b3;
      acc[1][0]+=a1*b0; acc[1][1]+=a1*b1; acc[1][2]+=a1*b2; acc[1][3]+=a1*b3;
      acc[2][0]+=a2*b0; acc[2][1]+=a2*b1; acc[2][2]+=a2*b2; acc[2][3]+=a2*b3;
      acc[3][0]+=a3*b0; acc[3][1]+=a3*b1; acc[3][2]+=a3*b2; acc[3][3]+=a3*b3;
    }
    __syncthreads();
  }
  #pragma unroll
  for (int j = 0; j < 4; j++){
    int v = n0 + ty*4 + j;
    float* dst = PO + (((size_t)b*128 + v)<<10) + m0 + tx*4;
    *(float4*)dst = make_float4(acc[0][j],acc[1][j],acc[2][j],acc[3][j]);
  }
}

// ---------------- gru slice helper — prologue only (fp32 weights)
__device__ __forceinline__ void gru_slice(const float* __restrict__ hs, const float* __restrict__ whh,
    const float* __restrict__ bhh, const float* __restrict__ gg, float* __restrict__ hdst,
    int r, int wid, int lane)
{
  #pragma unroll 1
  for (int jj = 0; jj < 8; jj++){
    int j = (r<<6) + (wid<<3) + jj;
    float sr = 0.f, sz = 0.f, sn = 0.f;
    #pragma unroll
    for (int u = 0; u < 4; u++){
      int k = lane + (u<<6);
      float hv = hs[k];
      sr += hv * whh[(size_t)j*256 + k];
      sz += hv * whh[(size_t)(j+256)*256 + k];
      sn += hv * whh[(size_t)(j+512)*256 + k];
    }
    sr = wred_sum(sr); sz = wred_sum(sz); sn = wred_sum(sn);
    if (lane == 0){
      float rr = 1.f/(1.f + expf(-(gg[j] + sr + bhh[j])));
      float zz = 1.f/(1.f + expf(-(gg[j+256] + sz + bhh[j+256])));
      float nn = tanhf(gg[j+512] + rr*(sn + bhh[j+512]));
      hdst[j] = (1.f - zz)*nn + zz*hs[j];
    }
  }
}

// ---------------- P10: initial GRU: hm1 -> h(0) (hbuf3 slot 0)
__global__ __launch_bounds__(512) void k_gq0(const float* __restrict__ hm1, const float* __restrict__ whh,
    const float* __restrict__ bhh, const float* __restrict__ gi, float* __restrict__ hbuf3)
{
  const int r = blockIdx.x, b = blockIdx.y;
  const int tid = threadIdx.x, lane = tid & 63, wid = tid >> 6;
  __shared__ float hs[256];
  if (tid < 256) hs[tid] = hm1[(b<<8) + tid];
  __syncthreads();
  gru_slice(hs, whh, bhh, gi + (size_t)b*768, hbuf3 + (b<<8), r, wid, lane);
}

// ---------------- P12: bf16-packed weights for the in-loop gru/query
// whhTjb[(g*256+j)*128 + kp] = {whh[g*256+j][2kp], whh[g*256+j][2kp+1]}   (row-stream per j)
// ahWTb[kp*512 + d]          = {ahW[d][2kp], ahW[d][2kp+1]}               (d-coalesced)
__global__ void k_tr(const float* __restrict__ whh, const float* __restrict__ ahW,
                     __hip_bfloat162* __restrict__ whhTjb, __hip_bfloat162* __restrict__ ahWTb)
{
  int i = blockIdx.x*256 + threadIdx.x;
  int stride = gridDim.x*256;
  for (int x = i; x < 3*256*128; x += stride){
    int kp = x & 127, j = (x >> 7) & 255, g = x >> 15;
    float lo = whh[(size_t)((g<<8)+j)*256 + (kp<<1)];
    float hi = whh[(size_t)((g<<8)+j)*256 + (kp<<1) + 1];
    __hip_bfloat162 h2; h2.x = __float2bfloat16(lo); h2.y = __float2bfloat16(hi);
    whhTjb[x] = h2;
  }
  for (int x = i; x < 128*512; x += stride){
    int d = x & 511, kp = x >> 9;
    float lo = ahW[(size_t)d*256 + (kp<<1)];
    float hi = ahW[(size_t)d*256 + (kp<<1) + 1];
    __hip_bfloat162 h2; h2.x = __float2bfloat16(lo); h2.y = __float2bfloat16(hi);
    ahWTb[x] = h2;
  }
}

// ================= per-step kernel: grid 256 (1 block/CU), t = 0..NT =================
// block (b=gid>>5, seg=gid&31, h=seg>>1, w0=(seg&1)<<5):
//  [t>0] softmax(e(t-1)); (seg==0) A(t)=A(t-1)+alpha write; prob(t-1) waves 0-3
//  [t<NT] halo+stencil+inline-query+tail -> e(t); (seg<8 && t<NT-1) gru slice h(t+1)[32j]
__global__ __launch_bounds__(512) void k_step(
  const float* __restrict__ dmask, const float* __restrict__ Mt,
  const float* __restrict__ trans,
  const float* __restrict__ acvW, const float* __restrict__ acvb,
  const float* __restrict__ PO, const float* __restrict__ SO,
  const float* __restrict__ CB, const float* __restrict__ embwO,
  const float* __restrict__ gi, const __hip_bfloat162* __restrict__ whhTjb,
  const float* __restrict__ bhh, const __hip_bfloat162* __restrict__ ahWTb,
  const float* __restrict__ ahb, float* __restrict__ hbuf3,
  float* __restrict__ abuf, float* __restrict__ ebuf,
  float* __restrict__ out, int t)
{
  const int gid = blockIdx.x, tid = threadIdx.x;
  const int lane = tid & 63, wv = tid >> 6;
  const int b = gid >> 5, seg = gid & 31, h = seg >> 1, w0 = (seg & 1) << 5;
  __shared__ float eo16[16][512];
  __shared__ float al[1024];
  __shared__ float as4[11][44];
  __shared__ float hq[256];
  __shared__ float red[18];

  const float* eprev = ebuf + (((t+1)&1)<<13);
  float*       ecurb = ebuf + ((t&1)<<13);
  const float* aprev = abuf + (((t+1)&1)<<13);
  float*       acur  = abuf + ((t&1)<<13);

  // stage h(t) for inline-query / gru (slot t%3; valid when t<NT)
  if (t < NT && tid < 256) hq[tid] = hbuf3[(t%3)*2048 + (b<<8) + tid];

  if (t > 0){
    // ---- softmax(e(t-1)) -> al
    float e0 = eprev[(b<<10)+tid], e1 = eprev[(b<<10)+512+tid];
    float dm0 = dmask[(b<<10)+tid], dm1 = dmask[(b<<10)+512+tid];
    float m = wred_max(fmaxf(e0, e1));
    if (lane == 0) red[wv] = m;
    __syncthreads();
    if (tid == 0){
      float g = red[0];
      #pragma unroll
      for (int k = 1; k < 8; k++) g = fmaxf(g, red[k]);
      red[16] = g;
    }
    __syncthreads();
    float g = red[16];
    float x0 = __expf(e0 - g)*dm0, x1 = __expf(e1 - g)*dm1;
    float s = wred_sum(x0 + x1);
    if (lane == 0) red[wv] = s;
    __syncthreads();
    if (tid == 0){
      float ss = 0.f;
      #pragma unroll
      for (int k = 0; k < 8; k++) ss += red[k];
      red[17] = ss;
    }
    __syncthreads();
    float inv = 1.f/(red[17] + 1e-10f);
    al[tid] = x0*inv; al[512+tid] = x1*inv;
    __syncthreads();
    // ---- A(t) write (block seg==0 owns it; not needed after t==NT-1's halo, skip at t==NT)
    if (seg == 0 && t < NT){
      acur[(b<<10)+tid]     = aprev[(b<<10)+tid]     + al[tid];
      acur[(b<<10)+512+tid] = aprev[(b<<10)+512+tid] + al[512+tid];
    }
    // ---- prob(t-1): waves 0..3, v = seg + 32*wv
    if (wv < 4){
      int v = seg + (wv<<5);
      if (v < NV){
        const float* POr = PO + (((size_t)b*128 + v)<<10);
        const float* hr = hbuf3 + ((t-1)%3)*2048 + (b<<8);
        const float* SOr = SO + (size_t)v*256;
        float a2 = 0.f;
        #pragma unroll
        for (int u = 0; u < 16; u++){ int p = lane + (u<<6); a2 += al[p]*POr[p]; }
        #pragma unroll
        for (int u = 0; u < 4; u++){ int k = lane + (u<<6); a2 += hr[k]*SOr[k]; }
        a2 = wred_sum(a2);
        if (lane == 0)
          out[((size_t)b*NT + (t-1))*NV + v] = a2 + CB[b*NV + v] + embwO[(((t-1)<<3)+b)*NV + v];
      }
    }
  }
  if (t < NT){
    // ---- halo: as4 = A(t-1) + alpha(t-1)  (44-wide rows, cols 42..43 zeroed)
    for (int idx = tid; idx < 11*44; idx += 512){
      int r = idx/44, c = idx - r*44;
      float v = 0.f;
      if (t > 0 && c < 42){
        int hi2 = h + r - 5, wi = w0 + c - 5;
        if ((unsigned)hi2 < 16u && (unsigned)wi < 64u){
          int p = (hi2<<6) + wi;
          v = aprev[(b<<10)+p] + al[p];
        }
      }
      as4[r][c] = v;
    }
    __syncthreads();
    // ---- stencil: thread owns d=tid; static hi-bounds row skip; float4 row loads
    float accw[32];
    #pragma unroll
    for (int w = 0; w < 32; w++) accw[w] = 0.f;
    if (t > 0){
      #pragma unroll 1
      for (int ki = 0; ki < 11; ki++){
        int hi2 = h + ki - 5;
        if ((unsigned)hi2 >= 16u) continue;
        float row[44];
        #pragma unroll
        for (int i4 = 0; i4 < 11; i4++)
          *(float4*)&row[i4*4] = *(const float4*)&as4[ki][i4*4];
        const float* mrow = Mt + ki*11*512 + tid;
        #pragma unroll
        for (int kj = 0; kj < 11; kj++){
          float m = mrow[kj*512];
          #pragma unroll
          for (int w = 0; w < 32; w++) accw[w] += row[kj + w]*m;
        }
      }
    }
    // ---- inline query: q[d=tid] = ahb[d] + h(t)·ahW[d]  (bf16x2 packed, d-coalesced)
    float q;
    {
      float s2 = 0.f;
      #pragma unroll 4
      for (int kp = 0; kp < 128; kp++){
        __hip_bfloat162 w = ahWTb[(kp<<9) + tid];
        s2 += hq[kp<<1]*__bfloat162float(w.x) + hq[(kp<<1)+1]*__bfloat162float(w.y);
      }
      q = s2 + ahb[tid];
    }
    // ---- tail: tanh -> eo16 transpose (2 chunks) -> wave-parallel reduce
    const float wav = acvW[tid];
    const float acb0 = acvb[0];
    const float* tbase = trans + (((size_t)(b<<10) + (h<<6) + w0))*NAD + tid;
    float* ecur = ecurb + (b<<10) + (h<<6) + w0;
    #pragma unroll 1
    for (int chunk = 0; chunk < 2; chunk++){
      __syncthreads();
      #pragma unroll
      for (int k = 0; k < 16; k++){
        int w = (chunk<<4) + k;
        eo16[k][tid] = wav * ftanh(q + tbase[(size_t)w*NAD] + accw[w]);
      }
      __syncthreads();
      #pragma unroll
      for (int u2 = 0; u2 < 2; u2++){
        int k = (wv<<1) + u2;
        float sum = 0.f;
        #pragma unroll
        for (int u = 0; u < 8; u++) sum += eo16[k][lane + (u<<6)];
        sum = wred_sum(sum);
        if (lane == 0) ecur[(chunk<<4) + k] = sum + acb0;
      }
    }
    // ---- gru slice: blocks seg<8 compute h(t+1)[j in 32*seg..+32), 4 j per wave (lanes 0..3)
    if (seg < 8 && t < NT-1 && lane < 4){
      int j = (seg<<5) + (wv<<2) + lane;
      const __hip_bfloat162* r0 = whhTjb + (size_t)j*128;
      const __hip_bfloat162* r1 = whhTjb + (size_t)(256+j)*128;
      const __hip_bfloat162* r2 = whhTjb + (size_t)(512+j)*128;
      float sr = 0.f, sz = 0.f, sn = 0.f;
      #pragma unroll 4
      for (int kp = 0; kp < 128; kp++){
        float h0 = hq[kp<<1], h1 = hq[(kp<<1)+1];
        __hip_bfloat162 wr = r0[kp], wz = r1[kp], wn = r2[kp];
        sr += h0*__bfloat162float(wr.x) + h1*__bfloat162float(wr.y);
        sz += h0*__bfloat162float(wz.x) + h1*__bfloat162float(wz.y);
        sn += h0*__bfloat162float(wn.x) + h1*__bfloat162float(wn.y);
      }
      const float* gg = gi + (size_t)(((t+1)<<3) + b)*768;
      float r = fsig(gg[j] + sr + bhh[j]);
      float z = fsig(gg[j+256] + sz + bhh[j+256]);
      float n = ftanh(gg[j+512] + r*(sn + bhh[j+512]));
      hbuf3[((t+1)%3)*2048 + (b<<8) + j] = (1.f - z)*n + z*hq[j];
    }
  }
}

extern "C" void kernel_launch(void* const* d_in, const int* in_sizes, int n_in,
                              void* d_out, int out_size, void* d_ws, size_t ws_size,
                              hipStream_t stream)
{
  const float* cnn  = (const float*)d_in[0];
  const float* cp   = (const float*)d_in[1];
  const float* im   = (const float*)d_in[2];
  const float* iW   = (const float*)d_in[3];
  const float* ib   = (const float*)d_in[4];
  const float* emb  = (const float*)d_in[5];
  const float* wih  = (const float*)d_in[6];
  const float* whh  = (const float*)d_in[7];
  const float* bih  = (const float*)d_in[8];
  const float* bhh  = (const float*)d_in[9];
  const float* ahW  = (const float*)d_in[10];
  const float* ahb  = (const float*)d_in[11];
  const float* acw  = (const float*)d_in[12];
  const float* awW  = (const float*)d_in[13];
  const float* acvW = (const float*)d_in[14];
  const float* acvb = (const float*)d_in[15];
  const float* ecw  = (const float*)d_in[16];
  const float* ecb  = (const float*)d_in[17];
  const float* sW   = (const float*)d_in[18];
  const float* sb   = (const float*)d_in[19];
  const float* ewW  = (const float*)d_in[20];
  const float* ewb  = (const float*)d_in[21];
  const float* cxW  = (const float*)d_in[22];
  const float* cxb  = (const float*)d_in[23];
  const float* cW   = (const float*)d_in[24];
  const float* cb   = (const float*)d_in[25];
  const float* oW   = (const float*)d_in[26];
  const float* ob   = (const float*)d_in[27];
  const int*   lab  = (const int*)d_in[28];
  float* out = (float*)d_out;
  float* ws = (float*)d_ws;

  float* dmask  = ws + 0;        // 8192
  float* ys     = ws + 8192;     // 8192
  float* xs     = ws + 16384;    // 8192
  float* idt    = ws + 24576;    // 128
  float* msum   = ws + 24704;    // 16
  float* avg    = ws + 24720;    // 5472
  float* cctx   = ws + 30192;    // 2048
  float* hm1    = ws + 32240;    // 2048
  float* hbuf3  = ws + 34288;    // 6144 (3 x 8 x 256)
  float* abuf   = ws + 40432;    // 16384 (2 x 8 x 1024)
  float* ebuf   = ws + 56816;    // 16384
  float* gi     = ws + 73200;    // 221184
  float* embw   = ws + 294384;   // 73728
  float* Mt     = ws + 368112;   // 61952
  float* SO     = ws + 430064;   // 28416
  float* CB     = ws + 458480;   // 896
  float* embwO  = ws + 459376;   // 32000
  float* CO     = ws + 491376;   // 87552
  __hip_bfloat162* whhTjb = (__hip_bfloat162*)(ws + 578928);  // 98304 words
  __hip_bfloat162* ahWTb  = (__hip_bfloat162*)(ws + 677232);  // 65536 words
  float* trans  = ws + 742768;   // 4194304
  float* PO     = ws + 4937072;  // 4194304   (total ~36.5 MB)

  k_p0<<<1, 256, 0, stream>>>(im, dmask, msum, ys, xs, idt, abuf);
  k_avg<<<456, 256, 0, stream>>>(cnn, dmask, msum, avg);
  k_init<<<256, 256, 0, stream>>>(avg, iW, ib, cp, cW, cb, hm1, cctx);
  k_pre<<<1024, 256, 0, stream>>>(lab, emb, wih, bih, ewW, ewb, gi, embw);
  k_trans<<<dim3(64, 8), 256, 0, stream>>>(cnn, ecw, ecb, ys, xs, idt, trans);
  k_mt<<<121, 256, 0, stream>>>(awW, acw, Mt);
  k_so<<<NV, 256, 0, stream>>>(sW, oW, sb, cxb, cctx, ob, SO, CB);
  k_embwO<<<NV, 512, 0, stream>>>(embw, oW, embwO);
  k_co<<<dim3(3, NV), 256, 0, stream>>>(cxW, oW, CO);
  k_gemm_PO<<<dim3(16, 2, 8), 256, 0, stream>>>(cnn, CO, PO);
  k_tr<<<128, 256, 0, stream>>>(whh, ahW, whhTjb, ahWTb);
  k_gq0<<<dim3(4, 8), 512, 0, stream>>>(hm1, whh, bhh, gi, hbuf3);

  for (int t = 0; t <= NT; t++){
    k_step<<<256, 512, 0, stream>>>(dmask, Mt, trans, acvW, acvb, PO, SO, CB, embwO,
                                    gi, whhTjb, bhh, ahWTb, ahb, hbuf3, abuf, ebuf, out, t);
  }
}

// Round 11
// 1474.163 us; speedup vs baseline: 4.8752x; 1.2427x over previous
//
#include <hip/hip_runtime.h>
#include <hip/hip_bf16.h>
#include <math.h>

#define NB 8
#define NC 684
#define NH 16
#define NW 64
#define NHW 1024
#define NHID 256
#define NAD 512
#define NV 111
#define NT 36
#define KPAD 704

typedef __attribute__((ext_vector_type(8))) short bf16x8;
typedef __attribute__((ext_vector_type(4))) float f32x4;

__device__ __forceinline__ float wred_sum(float v){
  #pragma unroll
  for (int o = 32; o > 0; o >>= 1) v += __shfl_xor(v, o, 64);
  return v;
}
__device__ __forceinline__ float wred_max(float v){
  #pragma unroll
  for (int o = 32; o > 0; o >>= 1) v = fmaxf(v, __shfl_xor(v, o, 64));
  return v;
}
__device__ __forceinline__ float fsig(float x){ return 1.f/(1.f + __expf(-x)); }
__device__ __forceinline__ float ftanh(float x){ float e = __expf(2.f*x); return 1.f - 2.f/(e + 1.f); }
__device__ __forceinline__ unsigned short f2bf(float f){
  __hip_bfloat16 h = __float2bfloat16(f);
  return *(unsigned short*)&h;
}
__device__ __forceinline__ float bf2f(unsigned short u){
  return __uint_as_float(((unsigned)u) << 16);
}

// ---------------- P0: dmask, msum, ys/xs, idt, zero abuf[0]
__global__ void k_p0(const float* __restrict__ im, float* __restrict__ dmask,
                     float* __restrict__ msum, float* __restrict__ ys, float* __restrict__ xs,
                     float* __restrict__ idt, float* __restrict__ abuf)
{
  const int tid = threadIdx.x; // 256 threads, 1 block
  for (int i = tid; i < NB*NHW; i += 256){
    int b = i >> 10, hw = i & 1023; int h = hw >> 6, w = hw & 63;
    dmask[i] = im[b*(256*1024) + (h*16)*1024 + (w*16)];
    abuf[i] = 0.f;
  }
  if (tid < 128) idt[tid] = expf(-(float)tid * (9.210340371976184f/128.f));
  __syncthreads();
  if (tid < 8){
    float s = 0.f;
    for (int i = 0; i < NHW; i++) s += dmask[tid*NHW + i];
    msum[tid] = s;
  }
  for (int p = tid; p < NB*NW; p += 256){
    int b = p >> 6, w = p & 63;
    float tot = 0.f;
    for (int h = 0; h < NH; h++) tot += dmask[b*NHW + h*64 + w];
    float inv = 6.283185307179586f/(tot + 1e-6f);
    float run = 0.f;
    for (int h = 0; h < NH; h++){ run += dmask[b*NHW + h*64 + w]; ys[b*NHW + h*64 + w] = run*inv; }
  }
  for (int p = tid; p < NB*NH; p += 256){
    int b = p >> 4, h = p & 15;
    float tot = 0.f;
    for (int w = 0; w < NW; w++) tot += dmask[b*NHW + h*64 + w];
    float inv = 6.283185307179586f/(tot + 1e-6f);
    float run = 0.f;
    for (int w = 0; w < NW; w++){ run += dmask[b*NHW + h*64 + w]; xs[b*NHW + h*64 + w] = run*inv; }
  }
}

// ---------------- P1: masked average
__global__ void k_avg(const float* __restrict__ cnn, const float* __restrict__ dmask,
                      const float* __restrict__ msum, float* __restrict__ avg)
{
  int gid = blockIdx.x*blockDim.x + threadIdx.x;
  int gw = gid >> 6, lane = gid & 63;
  int nw = (gridDim.x*blockDim.x) >> 6;
  for (int ow = gw; ow < NB*NC; ow += nw){
    int b = ow / NC;
    const float* base = cnn + (size_t)ow * NHW;
    const float* dm = dmask + b*NHW;
    float s = 0.f;
    for (int i = lane; i < NHW; i += 64) s += base[i]*dm[i];
    s = wred_sum(s);
    if (lane == 0) avg[ow] = s / msum[b];
  }
}

// ---------------- P2: hidden(-1) + counting_ctx
__global__ void k_init(const float* __restrict__ avg, const float* __restrict__ iW, const float* __restrict__ ib,
                       const float* __restrict__ cp, const float* __restrict__ cW, const float* __restrict__ cb,
                       float* __restrict__ hm1, float* __restrict__ cctx)
{
  int gid = blockIdx.x*blockDim.x + threadIdx.x;
  int gw = gid >> 6, lane = gid & 63;
  int nw = (gridDim.x*blockDim.x) >> 6;
  for (int ow = gw; ow < 2*NB*NHID; ow += nw){
    if (ow < NB*NHID){
      int b = ow >> 8, j = ow & 255;
      float s = 0.f;
      for (int k = lane; k < NC; k += 64) s += avg[b*NC + k]*iW[j*NC + k];
      s = wred_sum(s);
      if (lane == 0) hm1[ow] = tanhf(s + ib[j]);
    } else {
      int o = ow - NB*NHID; int b = o >> 8, j = o & 255;
      float s = 0.f;
      for (int k = lane; k < NV; k += 64) s += cp[b*NV + k]*cW[j*NV + k];
      s = wred_sum(s);
      if (lane == 0) cctx[o] = s + cb[j];
    }
  }
}

// ---------------- P3a: cnnT[b][hw][c] bf16 (c padded to 704), LDS-transposed tiles
__global__ __launch_bounds__(256) void k_cvt(const float* __restrict__ cnn, unsigned short* __restrict__ cnnT)
{
  const int hw0 = blockIdx.x << 6, c0 = blockIdx.y << 6, b = blockIdx.z;  // (16, 11, 8)
  __shared__ float T[64][65];
  const int tid = threadIdx.x;
  #pragma unroll
  for (int u = 0; u < 16; u++){
    int idx = tid + (u<<8);
    int cc = idx >> 6, mm = idx & 63;
    int c = c0 + cc;
    T[cc][mm] = (c < NC) ? cnn[((size_t)b*NC + c)*NHW + hw0 + mm] : 0.f;
  }
  __syncthreads();
  #pragma unroll
  for (int r0 = 0; r0 < 64; r0 += 8){
    int hwl = r0 + (tid >> 5);
    int cp = (tid & 31) << 1;
    unsigned u0 = f2bf(T[cp][hwl]);
    unsigned u1 = f2bf(T[cp+1][hwl]);
    *(unsigned*)&cnnT[((size_t)((b<<10) + hw0 + hwl))*KPAD + c0 + cp] = (u1 << 16) | u0;
  }
}

// ---------------- P3b: ewb[d][c] bf16 padded
__global__ void k_cvtw(const float* __restrict__ ew, unsigned short* __restrict__ ewb)
{
  int x = blockIdx.x*256 + threadIdx.x;
  if (x >= NAD*KPAD) return;
  int d = x / KPAD, c = x - d*KPAD;
  float v = (c < NC) ? ew[(size_t)d*NC + c] : 0.f;
  ewb[x] = f2bf(v);
}

// ---------------- P3c: trans = MFMA GEMM (cnnT @ ewb^T) + bias + sine pos-emb
// block = 4 waves; wave w: 16(m) x 64(n) strip. grid (128, 8).
__global__ __launch_bounds__(256) void k_mma_trans(const unsigned short* __restrict__ cnnT,
    const unsigned short* __restrict__ ewb, const float* __restrict__ eb,
    const float* __restrict__ ys, const float* __restrict__ xs,
    const float* __restrict__ idt, float* __restrict__ trans)
{
  const int m0 = blockIdx.x << 6;
  const int n0 = blockIdx.y << 6;
  const int b = m0 >> 10, hw0 = m0 & 1023;
  const int tid = threadIdx.x, lane = tid & 63, wv = tid >> 6;
  const int mrow = hw0 + (wv<<4) + (lane & 15);
  const int kgrp = (lane >> 4) << 3;
  const unsigned short* arow = cnnT + ((size_t)((b<<10) + mrow))*KPAD + kgrp;
  f32x4 acc[4];
  #pragma unroll
  for (int s = 0; s < 4; s++){ acc[s][0]=0.f; acc[s][1]=0.f; acc[s][2]=0.f; acc[s][3]=0.f; }
  #pragma unroll 2
  for (int k0 = 0; k0 < KPAD; k0 += 32){
    bf16x8 af = *(const bf16x8*)(arow + k0);
    #pragma unroll
    for (int s = 0; s < 4; s++){
      const unsigned short* brow = ewb + (size_t)(n0 + (s<<4) + (lane & 15))*KPAD + kgrp + k0;
      bf16x8 bf = *(const bf16x8*)brow;
      acc[s] = __builtin_amdgcn_mfma_f32_16x16x32_bf16(af, bf, acc[s], 0, 0, 0);
    }
  }
  #pragma unroll
  for (int r = 0; r < 4; r++){
    int hw = hw0 + (wv<<4) + ((lane>>4)<<2) + r;
    float ysv = ys[(b<<10)+hw], xsv = xs[(b<<10)+hw];
    #pragma unroll
    for (int s = 0; s < 4; s++){
      int d = n0 + (s<<4) + (lane & 15);
      float idtv = (d < 256) ? idt[d>>1] : idt[(d-256)>>1];
      float base = (d < 256) ? ysv : xsv;
      float arg = base*idtv;
      float pe = (d & 1) ? cosf(arg) : sinf(arg);
      trans[((size_t)((b<<10)+hw))*NAD + d] = acc[s][r] + eb[d] + pe;
    }
  }
}

// ---------------- P4: gi + embw for all steps
__global__ void k_pre(const int* __restrict__ labels, const float* __restrict__ emb,
    const float* __restrict__ wih, const float* __restrict__ bih,
    const float* __restrict__ ewW, const float* __restrict__ ewb2,
    float* __restrict__ gi, float* __restrict__ embw)
{
  int gid = blockIdx.x*blockDim.x + threadIdx.x;
  int gw = gid >> 6, lane = gid & 63;
  int nw = (gridDim.x*blockDim.x) >> 6;
  const int NGI = NT*NB*768;
  const int NEW_ = NT*NB*256;
  for (int ow = gw; ow < NGI + NEW_; ow += nw){
    if (ow < NGI){
      int i = ow % 768; int tb = ow / 768; int b = tb & 7, t = tb >> 3;
      int word = (t == 0) ? 1 : labels[b*NT + t - 1];
      const float* er = emb + (size_t)word*256;
      float s = 0.f;
      for (int k = lane; k < 256; k += 64) s += er[k]*wih[(size_t)i*256 + k];
      s = wred_sum(s);
      if (lane == 0) gi[ow] = s + bih[i];
    } else {
      int o = ow - NGI; int j = o & 255; int tb = o >> 8; int b = tb & 7, t = tb >> 3;
      int word = (t == 0) ? 1 : labels[b*NT + t - 1];
      const float* er = emb + (size_t)word*256;
      float s = 0.f;
      for (int k = lane; k < 256; k += 64) s += er[k]*ewW[(size_t)j*256 + k];
      s = wred_sum(s);
      if (lane == 0) embw[o] = s + ewb2[j];
    }
  }
}

// ---------------- P5: Mtb[tap][d] bf16
__global__ void k_mt(const float* __restrict__ aw, const float* __restrict__ acw, unsigned short* __restrict__ Mtb)
{
  __shared__ float col[512];
  int t = blockIdx.x; int tid = threadIdx.x;
  for (int c = tid; c < 512; c += 256) col[c] = acw[(size_t)c*121 + t];
  __syncthreads();
  for (int d = tid; d < 512; d += 256){
    float s = 0.f;
    const float4* r4 = (const float4*)(aw + (size_t)d*512);
    for (int k = 0; k < 128; k++){
      float4 w = r4[k];
      s += col[k*4+0]*w.x + col[k*4+1]*w.y + col[k*4+2]*w.z + col[k*4+3]*w.w;
    }
    Mtb[t*512 + d] = f2bf(s);
  }
}

// ---------------- P6: SO = oW@sW; CB
__global__ __launch_bounds__(256) void k_so(const float* __restrict__ sW, const float* __restrict__ oW,
    const float* __restrict__ sb, const float* __restrict__ cxb, const float* __restrict__ cctx,
    const float* __restrict__ ob, float* __restrict__ SO, float* __restrict__ CB)
{
  const int v = blockIdx.x; const int tid = threadIdx.x;
  float acc = 0.f;
  for (int j = 0; j < 256; j++) acc += sW[(size_t)j*256 + tid] * oW[(size_t)v*256 + j];
  SO[(size_t)v*256 + tid] = acc;
  if (tid < 8){
    float s = ob[v];
    for (int j = 0; j < 256; j++) s += (sb[j] + cxb[j] + cctx[tid*256 + j]) * oW[(size_t)v*256 + j];
    CB[tid*NV + v] = s;
  }
}

// ---------------- P7: embwO
__global__ __launch_bounds__(512) void k_embwO(const float* __restrict__ embw, const float* __restrict__ oW,
                                               float* __restrict__ embwO)
{
  const int v = blockIdx.x; const int tid = threadIdx.x;
  const int lane = tid & 63, wid = tid >> 6;
  __shared__ float ows[256];
  if (tid < 256) ows[tid] = oW[(size_t)v*256 + tid];
  __syncthreads();
  for (int tb = wid; tb < NT*NB; tb += 8){
    float acc = 0.f;
    #pragma unroll
    for (int u = 0; u < 4; u++){ int j = lane + (u<<6); acc += embw[(size_t)tb*256 + j]*ows[j]; }
    acc = wred_sum(acc);
    if (lane == 0) embwO[tb*NV + v] = acc;
  }
}

// ---------------- P8: COb[v][c] bf16 (padded; rows v>=111 zeroed)
__global__ __launch_bounds__(256) void k_co(const float* __restrict__ cxW, const float* __restrict__ oW,
                                            unsigned short* __restrict__ COb)
{
  const int c = blockIdx.x*256 + threadIdx.x;
  const int v = blockIdx.y;       // 0..127
  if (c >= KPAD) return;
  float acc = 0.f;
  if (v < NV && c < NC){
    for (int j = 0; j < 256; j++) acc += cxW[(size_t)j*NC + c] * oW[(size_t)v*256 + j];
  }
  COb[(size_t)v*KPAD + c] = f2bf(acc);
}

// ---------------- P9: PO = MFMA GEMM (cnnT @ COb^T). grid (16, 2, 8).
__global__ __launch_bounds__(256) void k_mma_PO(const unsigned short* __restrict__ cnnT,
    const unsigned short* __restrict__ COb, float* __restrict__ PO)
{
  const int m0 = blockIdx.x << 6;       // hw within b
  const int n0 = blockIdx.y << 6;       // v
  const int b = blockIdx.z;
  const int tid = threadIdx.x, lane = tid & 63, wv = tid >> 6;
  const int mrow = m0 + (wv<<4) + (lane & 15);
  const int kgrp = (lane >> 4) << 3;
  const unsigned short* arow = cnnT + ((size_t)((b<<10) + mrow))*KPAD + kgrp;
  f32x4 acc[4];
  #pragma unroll
  for (int s = 0; s < 4; s++){ acc[s][0]=0.f; acc[s][1]=0.f; acc[s][2]=0.f; acc[s][3]=0.f; }
  #pragma unroll 2
  for (int k0 = 0; k0 < KPAD; k0 += 32){
    bf16x8 af = *(const bf16x8*)(arow + k0);
    #pragma unroll
    for (int s = 0; s < 4; s++){
      const unsigned short* brow = COb + (size_t)(n0 + (s<<4) + (lane & 15))*KPAD + kgrp + k0;
      bf16x8 bf = *(const bf16x8*)brow;
      acc[s] = __builtin_amdgcn_mfma_f32_16x16x32_bf16(af, bf, acc[s], 0, 0, 0);
    }
  }
  #pragma unroll
  for (int s = 0; s < 4; s++){
    int v = n0 + (s<<4) + (lane & 15);
    #pragma unroll
    for (int r = 0; r < 4; r++){
      int hw = m0 + (wv<<4) + ((lane>>4)<<2) + r;
      PO[(((size_t)b*128 + v)<<10) + hw] = acc[s][r];
    }
  }
}

// ---------------- gru slice helper — prologue only (fp32 weights)
__device__ __forceinline__ void gru_slice(const float* __restrict__ hs, const float* __restrict__ whh,
    const float* __restrict__ bhh, const float* __restrict__ gg, float* __restrict__ hdst,
    int r, int wid, int lane)
{
  #pragma unroll 1
  for (int jj = 0; jj < 8; jj++){
    int j = (r<<6) + (wid<<3) + jj;
    float sr = 0.f, sz = 0.f, sn = 0.f;
    #pragma unroll
    for (int u = 0; u < 4; u++){
      int k = lane + (u<<6);
      float hv = hs[k];
      sr += hv * whh[(size_t)j*256 + k];
      sz += hv * whh[(size_t)(j+256)*256 + k];
      sn += hv * whh[(size_t)(j+512)*256 + k];
    }
    sr = wred_sum(sr); sz = wred_sum(sz); sn = wred_sum(sn);
    if (lane == 0){
      float rr = 1.f/(1.f + expf(-(gg[j] + sr + bhh[j])));
      float zz = 1.f/(1.f + expf(-(gg[j+256] + sz + bhh[j+256])));
      float nn = tanhf(gg[j+512] + rr*(sn + bhh[j+512]));
      hdst[j] = (1.f - zz)*nn + zz*hs[j];
    }
  }
}

// ---------------- P10: initial GRU: hm1 -> h(0) (hbuf3 slot 0)
__global__ __launch_bounds__(512) void k_gq0(const float* __restrict__ hm1, const float* __restrict__ whh,
    const float* __restrict__ bhh, const float* __restrict__ gi, float* __restrict__ hbuf3)
{
  const int r = blockIdx.x, b = blockIdx.y;
  const int tid = threadIdx.x, lane = tid & 63, wid = tid >> 6;
  __shared__ float hs[256];
  if (tid < 256) hs[tid] = hm1[(b<<8) + tid];
  __syncthreads();
  gru_slice(hs, whh, bhh, gi + (size_t)b*768, hbuf3 + (b<<8), r, wid, lane);
}

// ---------------- P12: bf16-packed weights for the in-loop gru/query
__global__ void k_tr(const float* __restrict__ whh, const float* __restrict__ ahW,
                     __hip_bfloat162* __restrict__ whhTjb, __hip_bfloat162* __restrict__ ahWTb)
{
  int i = blockIdx.x*256 + threadIdx.x;
  int stride = gridDim.x*256;
  for (int x = i; x < 3*256*128; x += stride){
    int kp = x & 127, j = (x >> 7) & 255, g = x >> 15;
    float lo = whh[(size_t)((g<<8)+j)*256 + (kp<<1)];
    float hi = whh[(size_t)((g<<8)+j)*256 + (kp<<1) + 1];
    __hip_bfloat162 h2; h2.x = __float2bfloat16(lo); h2.y = __float2bfloat16(hi);
    whhTjb[x] = h2;
  }
  for (int x = i; x < 128*512; x += stride){
    int d = x & 511, kp = x >> 9;
    float lo = ahW[(size_t)d*256 + (kp<<1)];
    float hi = ahW[(size_t)d*256 + (kp<<1) + 1];
    __hip_bfloat162 h2; h2.x = __float2bfloat16(lo); h2.y = __float2bfloat16(hi);
    ahWTb[x] = h2;
  }
}

// ================= per-step kernel: grid 256 (1 block/CU), t = 0..NT =================
__global__ __launch_bounds__(512) void k_step(
  const float* __restrict__ dmask, const unsigned short* __restrict__ Mtb,
  const float* __restrict__ trans,
  const float* __restrict__ acvW, const float* __restrict__ acvb,
  const float* __restrict__ PO, const float* __restrict__ SO,
  const float* __restrict__ CB, const float* __restrict__ embwO,
  const float* __restrict__ gi, const __hip_bfloat162* __restrict__ whhTjb,
  const float* __restrict__ bhh, const __hip_bfloat162* __restrict__ ahWTb,
  const float* __restrict__ ahb, float* __restrict__ hbuf3,
  float* __restrict__ abuf, float* __restrict__ ebuf,
  float* __restrict__ out, int t)
{
  const int gid = blockIdx.x, tid = threadIdx.x;
  const int lane = tid & 63, wv = tid >> 6;
  const int b = gid >> 5, seg = gid & 31, h = seg >> 1, w0 = (seg & 1) << 5;
  __shared__ float eo16[16][512];
  __shared__ float al[1024];
  __shared__ float as4[11][44];
  __shared__ float hq[256];
  __shared__ float red[18];

  const float* eprev = ebuf + (((t+1)&1)<<13);
  float*       ecurb = ebuf + ((t&1)<<13);
  const float* aprev = abuf + (((t+1)&1)<<13);
  float*       acur  = abuf + ((t&1)<<13);

  if (t < NT && tid < 256) hq[tid] = hbuf3[(t%3)*2048 + (b<<8) + tid];

  if (t > 0){
    // ---- softmax(e(t-1)) -> al
    float e0 = eprev[(b<<10)+tid], e1 = eprev[(b<<10)+512+tid];
    float dm0 = dmask[(b<<10)+tid], dm1 = dmask[(b<<10)+512+tid];
    float m = wred_max(fmaxf(e0, e1));
    if (lane == 0) red[wv] = m;
    __syncthreads();
    if (tid == 0){
      float g = red[0];
      #pragma unroll
      for (int k = 1; k < 8; k++) g = fmaxf(g, red[k]);
      red[16] = g;
    }
    __syncthreads();
    float g = red[16];
    float x0 = __expf(e0 - g)*dm0, x1 = __expf(e1 - g)*dm1;
    float s = wred_sum(x0 + x1);
    if (lane == 0) red[wv] = s;
    __syncthreads();
    if (tid == 0){
      float ss = 0.f;
      #pragma unroll
      for (int k = 0; k < 8; k++) ss += red[k];
      red[17] = ss;
    }
    __syncthreads();
    float inv = 1.f/(red[17] + 1e-10f);
    al[tid] = x0*inv; al[512+tid] = x1*inv;
    __syncthreads();
    if (seg == 0 && t < NT){
      acur[(b<<10)+tid]     = aprev[(b<<10)+tid]     + al[tid];
      acur[(b<<10)+512+tid] = aprev[(b<<10)+512+tid] + al[512+tid];
    }
    // ---- prob(t-1): waves 0..3, v = seg + 32*wv
    if (wv < 4){
      int v = seg + (wv<<5);
      if (v < NV){
        const float* POr = PO + (((size_t)b*128 + v)<<10);
        const float* hr = hbuf3 + ((t-1)%3)*2048 + (b<<8);
        const float* SOr = SO + (size_t)v*256;
        float a2 = 0.f;
        #pragma unroll
        for (int u = 0; u < 16; u++){ int p = lane + (u<<6); a2 += al[p]*POr[p]; }
        #pragma unroll
        for (int u = 0; u < 4; u++){ int k = lane + (u<<6); a2 += hr[k]*SOr[k]; }
        a2 = wred_sum(a2);
        if (lane == 0)
          out[((size_t)b*NT + (t-1))*NV + v] = a2 + CB[b*NV + v] + embwO[(((t-1)<<3)+b)*NV + v];
      }
    }
  }
  if (t < NT){
    // ---- halo: as4 = A(t-1) + alpha(t-1)  (44-wide rows, cols 42..43 zeroed)
    for (int idx = tid; idx < 11*44; idx += 512){
      int r = idx/44, c = idx - r*44;
      float v = 0.f;
      if (t > 0 && c < 42){
        int hi2 = h + r - 5, wi = w0 + c - 5;
        if ((unsigned)hi2 < 16u && (unsigned)wi < 64u){
          int p = (hi2<<6) + wi;
          v = aprev[(b<<10)+p] + al[p];
        }
      }
      as4[r][c] = v;
    }
    __syncthreads();
    // ---- stencil: thread owns d=tid; static row skip; float4 row loads; bf16 Mt
    float accw[32];
    #pragma unroll
    for (int w = 0; w < 32; w++) accw[w] = 0.f;
    if (t > 0){
      #pragma unroll 1
      for (int ki = 0; ki < 11; ki++){
        int hi2 = h + ki - 5;
        if ((unsigned)hi2 >= 16u) continue;
        float row[44];
        #pragma unroll
        for (int i4 = 0; i4 < 11; i4++)
          *(float4*)&row[i4*4] = *(const float4*)&as4[ki][i4*4];
        const unsigned short* mrow = Mtb + ki*11*512 + tid;
        #pragma unroll
        for (int kj = 0; kj < 11; kj++){
          float m = bf2f(mrow[kj*512]);
          #pragma unroll
          for (int w = 0; w < 32; w++) accw[w] += row[kj + w]*m;
        }
      }
    }
    // ---- inline query: q[d=tid]
    float q;
    {
      float s2 = 0.f;
      #pragma unroll 4
      for (int kp = 0; kp < 128; kp++){
        __hip_bfloat162 w = ahWTb[(kp<<9) + tid];
        s2 += hq[kp<<1]*__bfloat162float(w.x) + hq[(kp<<1)+1]*__bfloat162float(w.y);
      }
      q = s2 + ahb[tid];
    }
    // ---- tail: tanh -> eo16 transpose (2 chunks) -> wave-parallel reduce
    const float wav = acvW[tid];
    const float acb0 = acvb[0];
    const float* tbase = trans + (((size_t)(b<<10) + (h<<6) + w0))*NAD + tid;
    float* ecur = ecurb + (b<<10) + (h<<6) + w0;
    #pragma unroll 1
    for (int chunk = 0; chunk < 2; chunk++){
      __syncthreads();
      #pragma unroll
      for (int k = 0; k < 16; k++){
        int w = (chunk<<4) + k;
        eo16[k][tid] = wav * ftanh(q + tbase[(size_t)w*NAD] + accw[w]);
      }
      __syncthreads();
      #pragma unroll
      for (int u2 = 0; u2 < 2; u2++){
        int k = (wv<<1) + u2;
        float sum = 0.f;
        #pragma unroll
        for (int u = 0; u < 8; u++) sum += eo16[k][lane + (u<<6)];
        sum = wred_sum(sum);
        if (lane == 0) ecur[(chunk<<4) + k] = sum + acb0;
      }
    }
    // ---- gru: blocks seg<8; wave owns 4 j; 16 lanes k-split per j, shfl reduce
    if (seg < 8 && t < NT-1){
      int j = (seg<<5) + (wv<<2) + (lane>>4);
      int qg = lane & 15;
      const __hip_bfloat162* r0 = whhTjb + (size_t)j*128 + (qg<<3);
      const __hip_bfloat162* r1 = whhTjb + (size_t)(256+j)*128 + (qg<<3);
      const __hip_bfloat162* r2 = whhTjb + (size_t)(512+j)*128 + (qg<<3);
      float sr = 0.f, sz = 0.f, sn = 0.f;
      #pragma unroll
      for (int i = 0; i < 8; i++){
        int kp = (qg<<3) + i;
        float h0 = hq[kp<<1], h1 = hq[(kp<<1)+1];
        __hip_bfloat162 wr = r0[i], wz2 = r1[i], wn = r2[i];
        sr += h0*__bfloat162float(wr.x) + h1*__bfloat162float(wr.y);
        sz += h0*__bfloat162float(wz2.x) + h1*__bfloat162float(wz2.y);
        sn += h0*__bfloat162float(wn.x) + h1*__bfloat162float(wn.y);
      }
      #pragma unroll
      for (int o = 1; o < 16; o <<= 1){
        sr += __shfl_xor(sr, o, 64);
        sz += __shfl_xor(sz, o, 64);
        sn += __shfl_xor(sn, o, 64);
      }
      if (qg == 0){
        const float* gg = gi + (size_t)(((t+1)<<3) + b)*768;
        float r = fsig(gg[j] + sr + bhh[j]);
        float z = fsig(gg[j+256] + sz + bhh[j+256]);
        float n = ftanh(gg[j+512] + r*(sn + bhh[j+512]));
        hbuf3[((t+1)%3)*2048 + (b<<8) + j] = (1.f - z)*n + z*hq[j];
      }
    }
  }
}

extern "C" void kernel_launch(void* const* d_in, const int* in_sizes, int n_in,
                              void* d_out, int out_size, void* d_ws, size_t ws_size,
                              hipStream_t stream)
{
  const float* cnn  = (const float*)d_in[0];
  const float* cp   = (const float*)d_in[1];
  const float* im   = (const float*)d_in[2];
  const float* iW   = (const float*)d_in[3];
  const float* ib   = (const float*)d_in[4];
  const float* emb  = (const float*)d_in[5];
  const float* wih  = (const float*)d_in[6];
  const float* whh  = (const float*)d_in[7];
  const float* bih  = (const float*)d_in[8];
  const float* bhh  = (const float*)d_in[9];
  const float* ahW  = (const float*)d_in[10];
  const float* ahb  = (const float*)d_in[11];
  const float* acw  = (const float*)d_in[12];
  const float* awW  = (const float*)d_in[13];
  const float* acvW = (const float*)d_in[14];
  const float* acvb = (const float*)d_in[15];
  const float* ecw  = (const float*)d_in[16];
  const float* ecb  = (const float*)d_in[17];
  const float* sW   = (const float*)d_in[18];
  const float* sb   = (const float*)d_in[19];
  const float* ewW  = (const float*)d_in[20];
  const float* ewb2 = (const float*)d_in[21];
  const float* cxW  = (const float*)d_in[22];
  const float* cxb  = (const float*)d_in[23];
  const float* cW   = (const float*)d_in[24];
  const float* cb   = (const float*)d_in[25];
  const float* oW   = (const float*)d_in[26];
  const float* ob   = (const float*)d_in[27];
  const int*   lab  = (const int*)d_in[28];
  float* out = (float*)d_out;
  float* ws = (float*)d_ws;

  float* dmask  = ws + 0;        // 8192
  float* ys     = ws + 8192;     // 8192
  float* xs     = ws + 16384;    // 8192
  float* idt    = ws + 24576;    // 128
  float* msum   = ws + 24704;    // 16
  float* avg    = ws + 24720;    // 5472
  float* cctx   = ws + 30192;    // 2048
  float* hm1    = ws + 32240;    // 2048
  float* hbuf3  = ws + 34288;    // 6144
  float* abuf   = ws + 40432;    // 16384
  float* ebuf   = ws + 56816;    // 16384
  float* gi     = ws + 73200;    // 221184
  float* embw   = ws + 294384;   // 73728
  unsigned short* Mtb = (unsigned short*)(ws + 368112);   // 61952 ushort = 30976 words
  float* SO     = ws + 399088;   // 28416
  float* CB     = ws + 427504;   // 896
  float* embwO  = ws + 428400;   // 32000
  __hip_bfloat162* whhTjb = (__hip_bfloat162*)(ws + 460400);  // 98304 words
  __hip_bfloat162* ahWTb  = (__hip_bfloat162*)(ws + 558704);  // 65536 words
  unsigned short* cnnT = (unsigned short*)(ws + 624240);  // 8*1024*704 ushort = 2883584 words
  unsigned short* ewbb = (unsigned short*)(ws + 3507824); // 512*704 ushort = 180224 words
  unsigned short* COb  = (unsigned short*)(ws + 3688048); // 128*704 ushort = 45056 words
  float* trans  = ws + 3733104;  // 4194304
  float* PO     = ws + 7927408;  // 4194304   (total ~48.5 MB)

  k_p0<<<1, 256, 0, stream>>>(im, dmask, msum, ys, xs, idt, abuf);
  k_avg<<<456, 256, 0, stream>>>(cnn, dmask, msum, avg);
  k_init<<<256, 256, 0, stream>>>(avg, iW, ib, cp, cW, cb, hm1, cctx);
  k_pre<<<1024, 256, 0, stream>>>(lab, emb, wih, bih, ewW, ewb2, gi, embw);
  k_cvt<<<dim3(16, 11, 8), 256, 0, stream>>>(cnn, cnnT);
  k_cvtw<<<(NAD*KPAD + 255)/256, 256, 0, stream>>>(ecw, ewbb);
  k_mma_trans<<<dim3(128, 8), 256, 0, stream>>>(cnnT, ewbb, ecb, ys, xs, idt, trans);
  k_mt<<<121, 256, 0, stream>>>(awW, acw, Mtb);
  k_so<<<NV, 256, 0, stream>>>(sW, oW, sb, cxb, cctx, ob, SO, CB);
  k_embwO<<<NV, 512, 0, stream>>>(embw, oW, embwO);
  k_co<<<dim3(3, 128), 256, 0, stream>>>(cxW, oW, COb);
  k_mma_PO<<<dim3(16, 2, 8), 256, 0, stream>>>(cnnT, COb, PO);
  k_tr<<<128, 256, 0, stream>>>(whh, ahW, whhTjb, ahWTb);
  k_gq0<<<dim3(4, 8), 512, 0, stream>>>(hm1, whh, bhh, gi, hbuf3);

  for (int t = 0; t <= NT; t++){
    k_step<<<256, 512, 0, stream>>>(dmask, Mtb, trans, acvW, acvb, PO, SO, CB, embwO,
                                    gi, whhTjb, bhh, ahWTb, ahb, hbuf3, abuf, ebuf, out, t);
  }
}

// Round 12
// 1249.740 us; speedup vs baseline: 5.7507x; 1.1796x over previous
//
#include <hip/hip_runtime.h>
#include <hip/hip_bf16.h>
#include <math.h>

#define NB 8
#define NC 684
#define NH 16
#define NW 64
#define NHW 1024
#define NHID 256
#define NAD 512
#define NV 111
#define NT 36
#define KPAD 704

typedef __attribute__((ext_vector_type(8))) short bf16x8;
typedef __attribute__((ext_vector_type(4))) float f32x4;

__device__ __forceinline__ float wred_sum(float v){
  #pragma unroll
  for (int o = 32; o > 0; o >>= 1) v += __shfl_xor(v, o, 64);
  return v;
}
__device__ __forceinline__ float wred_max(float v){
  #pragma unroll
  for (int o = 32; o > 0; o >>= 1) v = fmaxf(v, __shfl_xor(v, o, 64));
  return v;
}
__device__ __forceinline__ float fsig(float x){ return 1.f/(1.f + __expf(-x)); }
__device__ __forceinline__ float ftanh(float x){ float e = __expf(2.f*x); return 1.f - 2.f/(e + 1.f); }
__device__ __forceinline__ unsigned short f2bf(float f){
  __hip_bfloat16 h = __float2bfloat16(f);
  return *(unsigned short*)&h;
}

// ---------------- P0
__global__ void k_p0(const float* __restrict__ im, float* __restrict__ dmask,
                     float* __restrict__ msum, float* __restrict__ ys, float* __restrict__ xs,
                     float* __restrict__ idt, float* __restrict__ abuf)
{
  const int tid = threadIdx.x;
  for (int i = tid; i < NB*NHW; i += 256){
    int b = i >> 10, hw = i & 1023; int h = hw >> 6, w = hw & 63;
    dmask[i] = im[b*(256*1024) + (h*16)*1024 + (w*16)];
    abuf[i] = 0.f;
  }
  if (tid < 128) idt[tid] = expf(-(float)tid * (9.210340371976184f/128.f));
  __syncthreads();
  if (tid < 8){
    float s = 0.f;
    for (int i = 0; i < NHW; i++) s += dmask[tid*NHW + i];
    msum[tid] = s;
  }
  for (int p = tid; p < NB*NW; p += 256){
    int b = p >> 6, w = p & 63;
    float tot = 0.f;
    for (int h = 0; h < NH; h++) tot += dmask[b*NHW + h*64 + w];
    float inv = 6.283185307179586f/(tot + 1e-6f);
    float run = 0.f;
    for (int h = 0; h < NH; h++){ run += dmask[b*NHW + h*64 + w]; ys[b*NHW + h*64 + w] = run*inv; }
  }
  for (int p = tid; p < NB*NH; p += 256){
    int b = p >> 4, h = p & 15;
    float tot = 0.f;
    for (int w = 0; w < NW; w++) tot += dmask[b*NHW + h*64 + w];
    float inv = 6.283185307179586f/(tot + 1e-6f);
    float run = 0.f;
    for (int w = 0; w < NW; w++){ run += dmask[b*NHW + h*64 + w]; xs[b*NHW + h*64 + w] = run*inv; }
  }
}

// ---------------- P1: masked average
__global__ void k_avg(const float* __restrict__ cnn, const float* __restrict__ dmask,
                      const float* __restrict__ msum, float* __restrict__ avg)
{
  int gid = blockIdx.x*blockDim.x + threadIdx.x;
  int gw = gid >> 6, lane = gid & 63;
  int nw = (gridDim.x*blockDim.x) >> 6;
  for (int ow = gw; ow < NB*NC; ow += nw){
    int b = ow / NC;
    const float* base = cnn + (size_t)ow * NHW;
    const float* dm = dmask + b*NHW;
    float s = 0.f;
    for (int i = lane; i < NHW; i += 64) s += base[i]*dm[i];
    s = wred_sum(s);
    if (lane == 0) avg[ow] = s / msum[b];
  }
}

// ---------------- P2: hidden(-1) + counting_ctx
__global__ void k_init(const float* __restrict__ avg, const float* __restrict__ iW, const float* __restrict__ ib,
                       const float* __restrict__ cp, const float* __restrict__ cW, const float* __restrict__ cb,
                       float* __restrict__ hm1, float* __restrict__ cctx)
{
  int gid = blockIdx.x*blockDim.x + threadIdx.x;
  int gw = gid >> 6, lane = gid & 63;
  int nw = (gridDim.x*blockDim.x) >> 6;
  for (int ow = gw; ow < 2*NB*NHID; ow += nw){
    if (ow < NB*NHID){
      int b = ow >> 8, j = ow & 255;
      float s = 0.f;
      for (int k = lane; k < NC; k += 64) s += avg[b*NC + k]*iW[j*NC + k];
      s = wred_sum(s);
      if (lane == 0) hm1[ow] = tanhf(s + ib[j]);
    } else {
      int o = ow - NB*NHID; int b = o >> 8, j = o & 255;
      float s = 0.f;
      for (int k = lane; k < NV; k += 64) s += cp[b*NV + k]*cW[j*NV + k];
      s = wred_sum(s);
      if (lane == 0) cctx[o] = s + cb[j];
    }
  }
}

// ---------------- P3a: cnnT[b][hw][c] bf16 (c padded to 704)
__global__ __launch_bounds__(256) void k_cvt(const float* __restrict__ cnn, unsigned short* __restrict__ cnnT)
{
  const int hw0 = blockIdx.x << 6, c0 = blockIdx.y << 6, b = blockIdx.z;  // (16, 11, 8)
  __shared__ float T[64][65];
  const int tid = threadIdx.x;
  #pragma unroll
  for (int u = 0; u < 16; u++){
    int idx = tid + (u<<8);
    int cc = idx >> 6, mm = idx & 63;
    int c = c0 + cc;
    T[cc][mm] = (c < NC) ? cnn[((size_t)b*NC + c)*NHW + hw0 + mm] : 0.f;
  }
  __syncthreads();
  #pragma unroll
  for (int r0 = 0; r0 < 64; r0 += 8){
    int hwl = r0 + (tid >> 5);
    int cp = (tid & 31) << 1;
    unsigned u0 = f2bf(T[cp][hwl]);
    unsigned u1 = f2bf(T[cp+1][hwl]);
    *(unsigned*)&cnnT[((size_t)((b<<10) + hw0 + hwl))*KPAD + c0 + cp] = (u1 << 16) | u0;
  }
}

// ---------------- P3b: ewb[d][c] bf16 padded
__global__ void k_cvtw(const float* __restrict__ ew, unsigned short* __restrict__ ewb)
{
  int x = blockIdx.x*256 + threadIdx.x;
  if (x >= NAD*KPAD) return;
  int d = x / KPAD, c = x - d*KPAD;
  float v = (c < NC) ? ew[(size_t)d*NC + c] : 0.f;
  ewb[x] = f2bf(v);
}

// ---------------- P3c: trans = MFMA GEMM + bias + sine pos-emb
__global__ __launch_bounds__(256) void k_mma_trans(const unsigned short* __restrict__ cnnT,
    const unsigned short* __restrict__ ewb, const float* __restrict__ eb,
    const float* __restrict__ ys, const float* __restrict__ xs,
    const float* __restrict__ idt, float* __restrict__ trans)
{
  const int m0 = blockIdx.x << 6;
  const int n0 = blockIdx.y << 6;
  const int b = m0 >> 10, hw0 = m0 & 1023;
  const int tid = threadIdx.x, lane = tid & 63, wv = tid >> 6;
  const int mrow = hw0 + (wv<<4) + (lane & 15);
  const int kgrp = (lane >> 4) << 3;
  const unsigned short* arow = cnnT + ((size_t)((b<<10) + mrow))*KPAD + kgrp;
  f32x4 acc[4];
  #pragma unroll
  for (int s = 0; s < 4; s++){ acc[s][0]=0.f; acc[s][1]=0.f; acc[s][2]=0.f; acc[s][3]=0.f; }
  #pragma unroll 2
  for (int k0 = 0; k0 < KPAD; k0 += 32){
    bf16x8 af = *(const bf16x8*)(arow + k0);
    #pragma unroll
    for (int s = 0; s < 4; s++){
      const unsigned short* brow = ewb + (size_t)(n0 + (s<<4) + (lane & 15))*KPAD + kgrp + k0;
      bf16x8 bf = *(const bf16x8*)brow;
      acc[s] = __builtin_amdgcn_mfma_f32_16x16x32_bf16(af, bf, acc[s], 0, 0, 0);
    }
  }
  #pragma unroll
  for (int r = 0; r < 4; r++){
    int hw = hw0 + (wv<<4) + ((lane>>4)<<2) + r;
    float ysv = ys[(b<<10)+hw], xsv = xs[(b<<10)+hw];
    #pragma unroll
    for (int s = 0; s < 4; s++){
      int d = n0 + (s<<4) + (lane & 15);
      float idtv = (d < 256) ? idt[d>>1] : idt[(d-256)>>1];
      float base = (d < 256) ? ysv : xsv;
      float arg = base*idtv;
      float pe = (d & 1) ? cosf(arg) : sinf(arg);
      trans[((size_t)((b<<10)+hw))*NAD + d] = acc[s][r] + eb[d] + pe;
    }
  }
}

// ---------------- P4a: per-word projections giW[v][768], embwW[v][256]
__global__ __launch_bounds__(256) void k_wproj(const float* __restrict__ emb, const float* __restrict__ wih,
    const float* __restrict__ bih, const float* __restrict__ ewW, const float* __restrict__ ewb2,
    float* __restrict__ giW, float* __restrict__ embwW)
{
  const int v = blockIdx.x, g = blockIdx.y;  // (111, 4)
  const int tid = threadIdx.x;
  __shared__ float er[256];
  er[tid] = emb[(size_t)v*256 + tid];
  __syncthreads();
  if (g < 3){
    int i = (g<<8) + tid;
    float s = 0.f;
    const float* wr = wih + (size_t)i*256;
    #pragma unroll 4
    for (int k = 0; k < 256; k++) s += er[k]*wr[k];
    giW[(size_t)v*768 + i] = s + bih[i];
  } else {
    float s = 0.f;
    const float* wr = ewW + (size_t)tid*256;
    #pragma unroll 4
    for (int k = 0; k < 256; k++) s += er[k]*wr[k];
    embwW[(size_t)v*256 + tid] = s + ewb2[tid];
  }
}

// ---------------- P4b: embwOW[v][u] = embwW[v]·oW[u]
__global__ __launch_bounds__(128) void k_ewo(const float* __restrict__ embwW, const float* __restrict__ oW,
                                             float* __restrict__ embwOW)
{
  const int v = blockIdx.x;
  const int u = threadIdx.x;
  __shared__ float ew[256];
  ew[u] = embwW[(size_t)v*256 + u];
  ew[128 + u] = embwW[(size_t)v*256 + 128 + u];
  __syncthreads();
  if (u < NV){
    float s = 0.f;
    const float* wr = oW + (size_t)u*256;
    #pragma unroll 4
    for (int k = 0; k < 256; k++) s += ew[k]*wr[k];
    embwOW[v*NV + u] = s;
  }
}

// ---------------- P5: MtT[d][tap] bf16, taps padded to 128
__global__ void k_mt(const float* __restrict__ aw, const float* __restrict__ acw, unsigned short* __restrict__ MtT)
{
  __shared__ float col[512];
  int t = blockIdx.x; int tid = threadIdx.x;   // 121 x 256
  for (int c = tid; c < 512; c += 256) col[c] = acw[(size_t)c*121 + t];
  __syncthreads();
  for (int d = tid; d < 512; d += 256){
    float s = 0.f;
    const float4* r4 = (const float4*)(aw + (size_t)d*512);
    for (int k = 0; k < 128; k++){
      float4 w = r4[k];
      s += col[k*4+0]*w.x + col[k*4+1]*w.y + col[k*4+2]*w.z + col[k*4+3]*w.w;
    }
    MtT[d*128 + t] = f2bf(s);
    if (t == 0){
      #pragma unroll
      for (int p = 121; p < 128; p++) MtT[d*128 + p] = 0;
    }
  }
}

// ---------------- P6: SO = oW@sW; CB
__global__ __launch_bounds__(256) void k_so(const float* __restrict__ sW, const float* __restrict__ oW,
    const float* __restrict__ sb, const float* __restrict__ cxb, const float* __restrict__ cctx,
    const float* __restrict__ ob, float* __restrict__ SO, float* __restrict__ CB)
{
  const int v = blockIdx.x; const int tid = threadIdx.x;
  float acc = 0.f;
  for (int j = 0; j < 256; j++) acc += sW[(size_t)j*256 + tid] * oW[(size_t)v*256 + j];
  SO[(size_t)v*256 + tid] = acc;
  if (tid < 8){
    float s = ob[v];
    for (int j = 0; j < 256; j++) s += (sb[j] + cxb[j] + cctx[tid*256 + j]) * oW[(size_t)v*256 + j];
    CB[tid*NV + v] = s;
  }
}

// ---------------- P8: COb[v][c] bf16
__global__ __launch_bounds__(256) void k_co(const float* __restrict__ cxW, const float* __restrict__ oW,
                                            unsigned short* __restrict__ COb)
{
  const int c = blockIdx.x*256 + threadIdx.x;
  const int v = blockIdx.y;       // 0..127
  if (c >= KPAD) return;
  float acc = 0.f;
  if (v < NV && c < NC){
    for (int j = 0; j < 256; j++) acc += cxW[(size_t)j*NC + c] * oW[(size_t)v*256 + j];
  }
  COb[(size_t)v*KPAD + c] = f2bf(acc);
}

// ---------------- P9: PO = MFMA GEMM
__global__ __launch_bounds__(256) void k_mma_PO(const unsigned short* __restrict__ cnnT,
    const unsigned short* __restrict__ COb, float* __restrict__ PO)
{
  const int m0 = blockIdx.x << 6;
  const int n0 = blockIdx.y << 6;
  const int b = blockIdx.z;
  const int tid = threadIdx.x, lane = tid & 63, wv = tid >> 6;
  const int mrow = m0 + (wv<<4) + (lane & 15);
  const int kgrp = (lane >> 4) << 3;
  const unsigned short* arow = cnnT + ((size_t)((b<<10) + mrow))*KPAD + kgrp;
  f32x4 acc[4];
  #pragma unroll
  for (int s = 0; s < 4; s++){ acc[s][0]=0.f; acc[s][1]=0.f; acc[s][2]=0.f; acc[s][3]=0.f; }
  #pragma unroll 2
  for (int k0 = 0; k0 < KPAD; k0 += 32){
    bf16x8 af = *(const bf16x8*)(arow + k0);
    #pragma unroll
    for (int s = 0; s < 4; s++){
      const unsigned short* brow = COb + (size_t)(n0 + (s<<4) + (lane & 15))*KPAD + kgrp + k0;
      bf16x8 bf = *(const bf16x8*)brow;
      acc[s] = __builtin_amdgcn_mfma_f32_16x16x32_bf16(af, bf, acc[s], 0, 0, 0);
    }
  }
  #pragma unroll
  for (int s = 0; s < 4; s++){
    int v = n0 + (s<<4) + (lane & 15);
    #pragma unroll
    for (int r = 0; r < 4; r++){
      int hw = m0 + (wv<<4) + ((lane>>4)<<2) + r;
      PO[(((size_t)b*128 + v)<<10) + hw] = acc[s][r];
    }
  }
}

// ---------------- gru slice helper — prologue only (fp32)
__device__ __forceinline__ void gru_slice(const float* __restrict__ hs, const float* __restrict__ whh,
    const float* __restrict__ bhh, const float* __restrict__ gg, float* __restrict__ hdst,
    int r, int wid, int lane)
{
  #pragma unroll 1
  for (int jj = 0; jj < 8; jj++){
    int j = (r<<6) + (wid<<3) + jj;
    float sr = 0.f, sz = 0.f, sn = 0.f;
    #pragma unroll
    for (int u = 0; u < 4; u++){
      int k = lane + (u<<6);
      float hv = hs[k];
      sr += hv * whh[(size_t)j*256 + k];
      sz += hv * whh[(size_t)(j+256)*256 + k];
      sn += hv * whh[(size_t)(j+512)*256 + k];
    }
    sr = wred_sum(sr); sz = wred_sum(sz); sn = wred_sum(sn);
    if (lane == 0){
      float rr = 1.f/(1.f + expf(-(gg[j] + sr + bhh[j])));
      float zz = 1.f/(1.f + expf(-(gg[j+256] + sz + bhh[j+256])));
      float nn = tanhf(gg[j+512] + rr*(sn + bhh[j+512]));
      hdst[j] = (1.f - zz)*nn + zz*hs[j];
    }
  }
}

// ---------------- P10: initial GRU (word0 = 1)
__global__ __launch_bounds__(512) void k_gq0(const float* __restrict__ hm1, const float* __restrict__ whh,
    const float* __restrict__ bhh, const float* __restrict__ giW, float* __restrict__ hbuf3)
{
  const int r = blockIdx.x, b = blockIdx.y;
  const int tid = threadIdx.x, lane = tid & 63, wid = tid >> 6;
  __shared__ float hs[256];
  if (tid < 256) hs[tid] = hm1[(b<<8) + tid];
  __syncthreads();
  gru_slice(hs, whh, bhh, giW + 768, hbuf3 + (b<<8), r, wid, lane);
}

// ---------------- P12: bf16-packed weights for in-loop gru/query
__global__ void k_tr(const float* __restrict__ whh, const float* __restrict__ ahW,
                     __hip_bfloat162* __restrict__ whhTjb, __hip_bfloat162* __restrict__ ahWTb)
{
  int i = blockIdx.x*256 + threadIdx.x;
  int stride = gridDim.x*256;
  for (int x = i; x < 3*256*128; x += stride){
    int kp = x & 127, j = (x >> 7) & 255, g = x >> 15;
    float lo = whh[(size_t)((g<<8)+j)*256 + (kp<<1)];
    float hi = whh[(size_t)((g<<8)+j)*256 + (kp<<1) + 1];
    __hip_bfloat162 h2; h2.x = __float2bfloat16(lo); h2.y = __float2bfloat16(hi);
    whhTjb[x] = h2;
  }
  for (int x = i; x < 128*512; x += stride){
    int d = x & 511, kp = x >> 9;
    float lo = ahW[(size_t)d*256 + (kp<<1)];
    float hi = ahW[(size_t)d*256 + (kp<<1) + 1];
    __hip_bfloat162 h2; h2.x = __float2bfloat16(lo); h2.y = __float2bfloat16(hi);
    ahWTb[x] = h2;
  }
}

// ================= per-step kernel: grid 256 (1 block/CU), t = 0..NT =================
__global__ __launch_bounds__(512) void k_step(
  const float* __restrict__ dmask, const unsigned short* __restrict__ MtT,
  const float* __restrict__ trans,
  const float* __restrict__ acvW, const float* __restrict__ acvb,
  const float* __restrict__ PO, const float* __restrict__ SO,
  const float* __restrict__ CB, const float* __restrict__ embwOW,
  const float* __restrict__ giW, const int* __restrict__ lab,
  const __hip_bfloat162* __restrict__ whhTjb,
  const float* __restrict__ bhh, const __hip_bfloat162* __restrict__ ahWTb,
  const float* __restrict__ ahb, float* __restrict__ hbuf3,
  float* __restrict__ abuf, float* __restrict__ ebuf,
  float* __restrict__ out, int t)
{
  const int gid = blockIdx.x, tid = threadIdx.x;
  const int lane = tid & 63, wv = tid >> 6;
  const int b = gid >> 5, seg = gid & 31, h = seg >> 1, w0 = (seg & 1) << 5;
  __shared__ float eo[32][516];
  __shared__ float al[1024];
  __shared__ float as4[11][44];
  __shared__ unsigned short Asb[32*136];
  __shared__ float hq[256];
  __shared__ float qs[512];
  __shared__ float red[18];

  const float* eprev = ebuf + (((t+1)&1)<<13);
  float*       ecurb = ebuf + ((t&1)<<13);
  const float* aprev = abuf + (((t+1)&1)<<13);
  float*       acur  = abuf + ((t&1)<<13);

  if (t < NT && tid < 256) hq[tid] = hbuf3[(t%3)*2048 + (b<<8) + tid];

  if (t > 0){
    // ---- softmax(e(t-1)) -> al
    float e0 = eprev[(b<<10)+tid], e1 = eprev[(b<<10)+512+tid];
    float dm0 = dmask[(b<<10)+tid], dm1 = dmask[(b<<10)+512+tid];
    float m = wred_max(fmaxf(e0, e1));
    if (lane == 0) red[wv] = m;
    __syncthreads();
    if (tid == 0){
      float g = red[0];
      #pragma unroll
      for (int k = 1; k < 8; k++) g = fmaxf(g, red[k]);
      red[16] = g;
    }
    __syncthreads();
    float g = red[16];
    float x0 = __expf(e0 - g)*dm0, x1 = __expf(e1 - g)*dm1;
    float s = wred_sum(x0 + x1);
    if (lane == 0) red[wv] = s;
    __syncthreads();
    if (tid == 0){
      float ss = 0.f;
      #pragma unroll
      for (int k = 0; k < 8; k++) ss += red[k];
      red[17] = ss;
    }
    __syncthreads();
    float inv = 1.f/(red[17] + 1e-10f);
    al[tid] = x0*inv; al[512+tid] = x1*inv;
    __syncthreads();
    if (seg == 0 && t < NT){
      acur[(b<<10)+tid]     = aprev[(b<<10)+tid]     + al[tid];
      acur[(b<<10)+512+tid] = aprev[(b<<10)+512+tid] + al[512+tid];
    }
    // ---- prob(t-1): waves 0..3, v = seg + 32*wv
    if (wv < 4){
      int v = seg + (wv<<5);
      if (v < NV){
        int wprev = (t-1 == 0) ? 1 : lab[b*NT + t - 2];
        const float* POr = PO + (((size_t)b*128 + v)<<10);
        const float* hr = hbuf3 + ((t-1)%3)*2048 + (b<<8);
        const float* SOr = SO + (size_t)v*256;
        float a2 = 0.f;
        #pragma unroll
        for (int u = 0; u < 16; u++){ int p = lane + (u<<6); a2 += al[p]*POr[p]; }
        #pragma unroll
        for (int u = 0; u < 4; u++){ int k = lane + (u<<6); a2 += hr[k]*SOr[k]; }
        a2 = wred_sum(a2);
        if (lane == 0)
          out[((size_t)b*NT + (t-1))*NV + v] = a2 + CB[b*NV + v] + embwOW[wprev*NV + v];
      }
    }
  }
  if (t < NT){
    // ---- halo: as4 = A(t-1) + alpha(t-1)
    for (int idx = tid; idx < 11*44; idx += 512){
      int r = idx/44, c = idx - r*44;
      float v = 0.f;
      if (t > 0 && c < 42){
        int hi2 = h + r - 5, wi = w0 + c - 5;
        if ((unsigned)hi2 < 16u && (unsigned)wi < 64u){
          int p = (hi2<<6) + wi;
          v = aprev[(b<<10)+p] + al[p];
        }
      }
      as4[r][c] = v;
    }
    // ---- inline query: q[d=tid] -> qs
    {
      float s2 = 0.f;
      #pragma unroll 4
      for (int kp = 0; kp < 128; kp++){
        __hip_bfloat162 w = ahWTb[(kp<<9) + tid];
        s2 += hq[kp<<1]*__bfloat162float(w.x) + hq[(kp<<1)+1]*__bfloat162float(w.y);
      }
      qs[tid] = s2 + ahb[tid];
    }
    __syncthreads();
    // ---- im2col: Asb[w][tap] bf16 (pitch 136; taps 121..127 zero)
    #pragma unroll
    for (int u = 0; u < 8; u++){
      int idx = tid + (u<<9);
      int w = idx >> 7, tap = idx & 127;
      float v = 0.f;
      if (tap < 121 && t > 0){
        int ki = tap/11, kj = tap - ki*11;
        v = as4[ki][w + kj];
      }
      Asb[w*136 + tap] = f2bf(v);
    }
    __syncthreads();
    // ---- MFMA stencil: E[32w][512d] = A[32][128] x MtT^T
    const int mh = wv & 1, ns = wv >> 1;
    const int kg = (lane >> 4) << 3;
    f32x4 acc[8];
    #pragma unroll
    for (int s = 0; s < 8; s++){ acc[s][0]=0.f; acc[s][1]=0.f; acc[s][2]=0.f; acc[s][3]=0.f; }
    if (t > 0){
      const unsigned short* ab = &Asb[((mh<<4) + (lane & 15))*136 + kg];
      #pragma unroll
      for (int k0 = 0; k0 < 128; k0 += 32){
        bf16x8 af = *(const bf16x8*)(ab + k0);
        #pragma unroll
        for (int s = 0; s < 8; s++){
          const unsigned short* brow = MtT + (size_t)((ns<<7) + (s<<4) + (lane & 15))*128 + kg + k0;
          bf16x8 bf = *(const bf16x8*)brow;
          acc[s] = __builtin_amdgcn_mfma_f32_16x16x32_bf16(af, bf, acc[s], 0, 0, 0);
        }
      }
    }
    // ---- epilogue: eo[w][d] = wav[d]*tanh(q[d] + trans + acc)
    const float acb0 = acvb[0];
    #pragma unroll
    for (int s = 0; s < 8; s++){
      int d = (ns<<7) + (s<<4) + (lane & 15);
      float wav = acvW[d];
      float qd = qs[d];
      #pragma unroll
      for (int r = 0; r < 4; r++){
        int w = (mh<<4) + ((lane>>4)<<2) + r;
        int hw = (h<<6) + w0 + w;
        float tv = trans[((size_t)((b<<10)+hw))*NAD + d];
        eo[w][d] = wav * ftanh(qd + tv + acc[s][r]);
      }
    }
    __syncthreads();
    // ---- reduce: wave wv owns w = wv*4..+3
    float* ecur = ecurb + (b<<10) + (h<<6) + w0;
    #pragma unroll
    for (int k = 0; k < 4; k++){
      int w = (wv<<2) + k;
      float sum = 0.f;
      #pragma unroll
      for (int u = 0; u < 8; u++) sum += eo[w][lane + (u<<6)];
      sum = wred_sum(sum);
      if (lane == 0) ecur[w] = sum + acb0;
    }
    // ---- gru: blocks seg<8; wave owns 4 j; 16 lanes k-split per j
    if (seg < 8 && t < NT-1){
      int j = (seg<<5) + (wv<<2) + (lane>>4);
      int qg = lane & 15;
      const __hip_bfloat162* r0 = whhTjb + (size_t)j*128 + (qg<<3);
      const __hip_bfloat162* r1 = whhTjb + (size_t)(256+j)*128 + (qg<<3);
      const __hip_bfloat162* r2 = whhTjb + (size_t)(512+j)*128 + (qg<<3);
      float sr = 0.f, sz = 0.f, sn = 0.f;
      #pragma unroll
      for (int i = 0; i < 8; i++){
        int kp = (qg<<3) + i;
        float h0 = hq[kp<<1], h1 = hq[(kp<<1)+1];
        __hip_bfloat162 wr = r0[i], wz2 = r1[i], wn = r2[i];
        sr += h0*__bfloat162float(wr.x) + h1*__bfloat162float(wr.y);
        sz += h0*__bfloat162float(wz2.x) + h1*__bfloat162float(wz2.y);
        sn += h0*__bfloat162float(wn.x) + h1*__bfloat162float(wn.y);
      }
      #pragma unroll
      for (int o = 1; o < 16; o <<= 1){
        sr += __shfl_xor(sr, o, 64);
        sz += __shfl_xor(sz, o, 64);
        sn += __shfl_xor(sn, o, 64);
      }
      if (qg == 0){
        int wnext = lab[b*NT + t];
        const float* gg = giW + (size_t)wnext*768;
        float r = fsig(gg[j] + sr + bhh[j]);
        float z = fsig(gg[j+256] + sz + bhh[j+256]);
        float n = ftanh(gg[j+512] + r*(sn + bhh[j+512]));
        hbuf3[((t+1)%3)*2048 + (b<<8) + j] = (1.f - z)*n + z*hq[j];
      }
    }
  }
}

extern "C" void kernel_launch(void* const* d_in, const int* in_sizes, int n_in,
                              void* d_out, int out_size, void* d_ws, size_t ws_size,
                              hipStream_t stream)
{
  const float* cnn  = (const float*)d_in[0];
  const float* cp   = (const float*)d_in[1];
  const float* im   = (const float*)d_in[2];
  const float* iW   = (const float*)d_in[3];
  const float* ib   = (const float*)d_in[4];
  const float* emb  = (const float*)d_in[5];
  const float* wih  = (const float*)d_in[6];
  const float* whh  = (const float*)d_in[7];
  const float* bih  = (const float*)d_in[8];
  const float* bhh  = (const float*)d_in[9];
  const float* ahW  = (const float*)d_in[10];
  const float* ahb  = (const float*)d_in[11];
  const float* acw  = (const float*)d_in[12];
  const float* awW  = (const float*)d_in[13];
  const float* acvW = (const float*)d_in[14];
  const float* acvb = (const float*)d_in[15];
  const float* ecw  = (const float*)d_in[16];
  const float* ecb  = (const float*)d_in[17];
  const float* sW   = (const float*)d_in[18];
  const float* sb   = (const float*)d_in[19];
  const float* ewW  = (const float*)d_in[20];
  const float* ewb2 = (const float*)d_in[21];
  const float* cxW  = (const float*)d_in[22];
  const float* cxb  = (const float*)d_in[23];
  const float* cW   = (const float*)d_in[24];
  const float* cb   = (const float*)d_in[25];
  const float* oW   = (const float*)d_in[26];
  const float* ob   = (const float*)d_in[27];
  const int*   lab  = (const int*)d_in[28];
  float* out = (float*)d_out;
  float* ws = (float*)d_ws;

  float* dmask  = ws + 0;        // 8192
  float* ys     = ws + 8192;     // 8192
  float* xs     = ws + 16384;    // 8192
  float* idt    = ws + 24576;    // 128
  float* msum   = ws + 24704;    // 16
  float* avg    = ws + 24720;    // 5472
  float* cctx   = ws + 30192;    // 2048
  float* hm1    = ws + 32240;    // 2048
  float* hbuf3  = ws + 34288;    // 6144
  float* abuf   = ws + 40432;    // 16384
  float* ebuf   = ws + 56816;    // 16384
  float* giW    = ws + 73200;    // 85248
  float* embwW  = ws + 158448;   // 28416
  float* embwOW = ws + 186864;   // 12352
  unsigned short* MtT = (unsigned short*)(ws + 199216);   // 65536 ushort = 32768 words
  float* SO     = ws + 231984;   // 28416
  float* CB     = ws + 260400;   // 896
  __hip_bfloat162* whhTjb = (__hip_bfloat162*)(ws + 261296);  // 98304 words
  __hip_bfloat162* ahWTb  = (__hip_bfloat162*)(ws + 359600);  // 65536 words
  unsigned short* cnnT = (unsigned short*)(ws + 425136);  // 2883584 words
  unsigned short* ewbb = (unsigned short*)(ws + 3308720); // 180224 words
  unsigned short* COb  = (unsigned short*)(ws + 3488944); // 45056 words
  float* trans  = ws + 3534000;  // 4194304
  float* PO     = ws + 7728304;  // 4194304  (total ~47.7 MB)

  k_p0<<<1, 256, 0, stream>>>(im, dmask, msum, ys, xs, idt, abuf);
  k_avg<<<456, 256, 0, stream>>>(cnn, dmask, msum, avg);
  k_init<<<256, 256, 0, stream>>>(avg, iW, ib, cp, cW, cb, hm1, cctx);
  k_wproj<<<dim3(NV, 4), 256, 0, stream>>>(emb, wih, bih, ewW, ewb2, giW, embwW);
  k_ewo<<<NV, 128, 0, stream>>>(embwW, oW, embwOW);
  k_cvt<<<dim3(16, 11, 8), 256, 0, stream>>>(cnn, cnnT);
  k_cvtw<<<(NAD*KPAD + 255)/256, 256, 0, stream>>>(ecw, ewbb);
  k_mma_trans<<<dim3(128, 8), 256, 0, stream>>>(cnnT, ewbb, ecb, ys, xs, idt, trans);
  k_mt<<<121, 256, 0, stream>>>(awW, acw, MtT);
  k_so<<<NV, 256, 0, stream>>>(sW, oW, sb, cxb, cctx, ob, SO, CB);
  k_co<<<dim3(3, 128), 256, 0, stream>>>(cxW, oW, COb);
  k_mma_PO<<<dim3(16, 2, 8), 256, 0, stream>>>(cnnT, COb, PO);
  k_tr<<<128, 256, 0, stream>>>(whh, ahW, whhTjb, ahWTb);
  k_gq0<<<dim3(4, 8), 512, 0, stream>>>(hm1, whh, bhh, giW, hbuf3);

  for (int t = 0; t <= NT; t++){
    k_step<<<256, 512, 0, stream>>>(dmask, MtT, trans, acvW, acvb, PO, SO, CB, embwOW,
                                    giW, lab, whhTjb, bhh, ahWTb, ahb, hbuf3, abuf, ebuf, out, t);
  }
}